// Round 11
// baseline (1436.883 us; speedup 1.0000x reference)
//
#include <hip/hip_runtime.h>
#include <hip/hip_bf16.h>
#include <math.h>

using bf16 = __hip_bfloat16;
typedef __attribute__((ext_vector_type(8))) short s8v;
typedef __attribute__((ext_vector_type(4))) float f4v;

#define MTOT 65536   // B*T
#define TLEN 2048
#define NCHUNK 32
#define TCH 64

__device__ __forceinline__ float b2f(bf16 x) { return __bfloat162float(x); }
__device__ __forceinline__ bf16 f2b(float x) { return __float2bfloat16(x); }
__device__ __forceinline__ float bits2f(unsigned short u) {
    unsigned int x = ((unsigned int)u) << 16; float f; __builtin_memcpy(&f, &x, 4); return f;
}
__device__ __forceinline__ unsigned short f2bits(float x) {
    bf16 h = f2b(x); unsigned short u; __builtin_memcpy(&u, &h, 2); return u;
}

// flagged load: f32 buffer if f!=0 else bf16 buffer
__device__ __forceinline__ float ldf(const void* p, size_t i, int f) {
    return f ? ((const float*)p)[i] : b2f(((const bf16*)p)[i]);
}

__device__ __forceinline__ void ld_g2l(const void* g, void* l) {
    __builtin_amdgcn_global_load_lds(
        (const __attribute__((address_space(1))) void*)g,
        (__attribute__((address_space(3))) void*)l,
        16, 0, 0);
}

// ---------------- dtype detection ----------------
__global__ void detect_k(const unsigned short* __restrict__ x, int* __restrict__ flag) {
    int tid = threadIdx.x;
    int cnt = 0;
    for (int i = tid; i < 8192; i += 256) {
        int e = (x[i] >> 7) & 0xFF;
        if (e == 0 || e == 0xFF) cnt++;
    }
    __shared__ int red[256];
    red[tid] = cnt;
    __syncthreads();
    for (int s = 128; s > 0; s >>= 1) {
        if (tid < s) red[tid] += red[tid + s];
        __syncthreads();
    }
    if (tid == 0) flag[0] = (red[0] >= 2) ? 1 : 0;
}

// x4-vectorized convert
__global__ void cvt_k4(const void* __restrict__ src, bf16* __restrict__ dst, int n,
                       const int* __restrict__ flag) {
    int f = *flag;
    int i = (blockIdx.x * 256 + threadIdx.x) * 4;
    if (i + 3 < n) {
#pragma unroll
        for (int k = 0; k < 4; k++) dst[i + k] = f2b(ldf(src, i + k, f));
    } else {
        for (int k = 0; k < 4 && i + k < n; k++) dst[i + k] = f2b(ldf(src, i + k, f));
    }
}

// merged small-tensor converts (60 blocks)
__global__ void cvt_small(const void* b_enc, const void* Dp, const void* b1, const void* b2,
                          const void* bn_s, const void* bn_b, const void* W_out, const void* b_out,
                          bf16* b_encb, bf16* Db, bf16* b1b, bf16* b2b, bf16* bnsb, bf16* bnbb,
                          bf16* Woutb, bf16* boutb, const int* __restrict__ flag) {
    int f = *flag;
    int blk = blockIdx.x, t = threadIdx.x;
    const void* src; bf16* dst; int base, n;
    if (blk < 1)       { src = b_enc; dst = b_encb; base = blk;      n = 256; }
    else if (blk < 7)  { src = Dp;    dst = Db;     base = blk - 1;  n = 1536; }
    else if (blk < 31) { src = b1;    dst = b1b;    base = blk - 7;  n = 6144; }
    else if (blk < 37) { src = b2;    dst = b2b;    base = blk - 31; n = 1536; }
    else if (blk < 43) { src = bn_s;  dst = bnsb;   base = blk - 37; n = 1536; }
    else if (blk < 49) { src = bn_b;  dst = bnbb;   base = blk - 43; n = 1536; }
    else if (blk < 59) { src = W_out; dst = Woutb;  base = blk - 49; n = 2560; }
    else               { src = b_out; dst = boutb;  base = 0;        n = 10; }
    int i = base * 256 + t;
    if (i < n) dst[i] = f2b(ldf(src, i, f));
}

__global__ void lamgam_k(const void* __restrict__ nu, const void* __restrict__ th,
                         float* __restrict__ lamb, float* __restrict__ gamt,
                         const int* __restrict__ flag) {
    int f = *flag;
    int g = blockIdx.x * 256 + threadIdx.x;  // 1536
    float nl = ldf(nu, g, f), tl = ldf(th, g, f);
    float mag = expf(-expf(nl));
    float ang = expf(tl);
    lamb[g * 2] = mag * cosf(ang);
    lamb[g * 2 + 1] = mag * sinf(ang);
    gamt[g] = sqrtf(fmaxf(1.f - mag * mag, 1e-12f));
}

// =====================================================================
// GEMM out[m,n] = sum_k A[m,k]*W[n,k] (+epilogue). 128m x 64n tile,
// 4 waves (each 64x32), BK=32, 3-buffer LDS ring (36KB).
// SINGLE barrier per K-step:
//   vmcnt(3) -> s_barrier -> stage(t+2) -> ds_read buf[t%3] -> MFMA
// Safety: every wave lgkm-waits before MFMA(t-1) (data dep), so crossing
// barrier(t) proves all reads of buf[(t-1)%3] RETIRED; stage(t+2) (which
// overwrites that buffer) is issued only after barrier(t). vmcnt(3):
// only stage(t+1)'s 3 reqs are younger than stage(t) at the wait point
// (vmcnt retires oldest-first). Tail -> vmcnt(0). No lapping: a wave
// cannot pass barrier(t+2) until all finished compute(t+1).
// NBN column-siblings of an M-tile land on the same XCD (L2 A reuse).
// EPI 1: +bias -> outB & outB2, + BN-stats partials      (encoder)
// EPI 2: +Dv[n]*(a[n]*aux+c[n]) -> bf16                  (LRU C-out)
// EPI 5: v+bias+aux[m,n] -> bf16, + BN-stats partials    (W2 + residual;
//        the sum-partial doubles as the pooling partial for the head)
// EPI 6: +fbias[n] (fp32) -> bf16, + FUSED LRU CHUNK CARRY (r9 notes)
// =====================================================================
template<int KK, int NBN, int EPI>
__global__ __launch_bounds__(256)
void gemm_v7(const bf16* __restrict__ A, const bf16* __restrict__ W,
             bf16* __restrict__ outB, bf16* __restrict__ outB2, int ldo,
             const bf16* __restrict__ bias,
             const bf16* __restrict__ Dv, const bf16* __restrict__ aux,
             const float* __restrict__ fstats, float* __restrict__ spart,
             const float* __restrict__ lamp, float* __restrict__ carry)
{
    constexpr int LG = (NBN == 8) ? 3 : 2;
    const int id = blockIdx.x;
    const int xcd = id & 7, q = id >> 3;
    const int bn = q & (NBN - 1);
    const int bm = (q >> LG) * 8 + xcd;

    const int tid = threadIdx.x;
    const int lane = tid & 63, wv = tid >> 6;
    const int wm = wv >> 1, wn = wv & 1;
    const int quad = lane >> 4, cl = lane & 15;

    __shared__ __align__(16) short As[3][128 * 32];
    __shared__ __align__(16) short Ws[3][64 * 32];
    __shared__ float sred[256];

    const char* Ab = (const char*)A + (size_t)bm * 128 * ((size_t)KK * 2);
    const char* Wb = (const char*)W + (size_t)bn * 64 * ((size_t)KK * 2);
    constexpr int ldb = KK * 2;

    auto stage = [&](int t, int bi) {
        const int kb = t * 64;
#pragma unroll
        for (int it = 0; it < 2; ++it) {
            int G = it * 256 + tid;
            int r = G >> 2;
            int gl = (G & 3) ^ ((r >> 1) & 3);
            ld_g2l(Ab + (size_t)r * ldb + kb + gl * 16,
                   (char*)As[bi] + (it * 4 + wv) * 1024);
        }
        {
            int r = tid >> 2;
            int gl = (tid & 3) ^ ((r >> 1) & 3);
            ld_g2l(Wb + (size_t)r * ldb + kb + gl * 16,
                   (char*)Ws[bi] + wv * 1024);
        }
    };

    f4v acc[4][2];
#pragma unroll
    for (int i = 0; i < 4; i++)
#pragma unroll
        for (int j = 0; j < 2; j++) acc[i][j] = (f4v){0.f, 0.f, 0.f, 0.f};

    constexpr int NT = KK >> 5;
    stage(0, 0);
    if (NT > 1) stage(1, 1);
#pragma unroll
    for (int t = 0; t < NT; ++t) {
        if (t + 1 < NT) {
            asm volatile("s_waitcnt vmcnt(3)" ::: "memory");
        } else {
            asm volatile("s_waitcnt vmcnt(0)" ::: "memory");
        }
        asm volatile("s_barrier" ::: "memory");
        if (t + 2 < NT) stage(t + 2, (t + 2) % 3);
        const char* Ac = (const char*)As[t % 3];
        const char* Wc = (const char*)Ws[t % 3];
        s8v af[4], bw[2];
#pragma unroll
        for (int i = 0; i < 4; i++) {
            int r = wm * 64 + i * 16 + cl;
            af[i] = *(const s8v*)(Ac + r * 64 + ((quad ^ ((r >> 1) & 3)) * 16));
        }
#pragma unroll
        for (int j = 0; j < 2; j++) {
            int r = wn * 32 + j * 16 + cl;
            bw[j] = *(const s8v*)(Wc + r * 64 + ((quad ^ ((r >> 1) & 3)) * 16));
        }
#pragma unroll
        for (int i = 0; i < 4; i++)
#pragma unroll
            for (int j = 0; j < 2; j++)
                acc[i][j] = __builtin_amdgcn_mfma_f32_16x16x32_bf16(af[i], bw[j], acc[i][j], 0, 0, 0);
    }

    const size_t ld = (size_t)ldo;
    constexpr bool STATS = (EPI == 1 || EPI == 5);
#pragma unroll
    for (int j = 0; j < 2; j++) {
        float ss = 0.f, ss2 = 0.f;
        const int n = bn * 64 + wn * 32 + j * 16 + cl;
        // ---- carry-weight tables (EPI 6 only) ----
        float Er[4], Ei[4], Cr[4], Cim[4];
        if constexpr (EPI == 6) {
            int h = n >> 1;
            float lr = lamp[h * 2], li = lamp[h * 2 + 1];
            float a2r = lr * lr - li * li, a2i = 2.f * lr * li;          // lam^2
            float a3r = a2r * lr - a2i * li, a3i = a2r * li + a2i * lr;  // lam^3
            float l4r = a2r * a2r - a2i * a2i, l4i = 2.f * a2r * a2i;    // lam^4
            float l8r = l4r * l4r - l4i * l4i, l8i = 2.f * l4r * l4i;
            float l12r = l8r * l4r - l8i * l4i, l12i = l8r * l4i + l8i * l4r;
            float Br = (quad == 0) ? l12r : (quad == 1) ? l8r : (quad == 2) ? l4r : 1.f;
            float Bi = (quad == 0) ? l12i : (quad == 1) ? l8i : (quad == 2) ? l4i : 0.f;
            float Ar[4] = { a3r, a2r, lr, 1.f };
            float Ai[4] = { a3i, a2i, li, 0.f };
#pragma unroll
            for (int r4 = 0; r4 < 4; r4++) {
                Er[r4] = Ar[r4] * Br - Ai[r4] * Bi;
                Ei[r4] = Ar[r4] * Bi + Ai[r4] * Br;
            }
            float l16r = l12r * l4r - l12i * l4i, l16i = l12r * l4i + l12i * l4r;
            float l32r = l16r * l16r - l16i * l16i, l32i = 2.f * l16r * l16i;
            float l48r = l32r * l16r - l32i * l16i, l48i = l32r * l16i + l32i * l16r;
            Cr[0] = l48r; Cim[0] = l48i;   // i=0 -> lam^48
            Cr[1] = l32r; Cim[1] = l32i;
            Cr[2] = l16r; Cim[2] = l16i;
            Cr[3] = 1.f;  Cim[3] = 0.f;
        }
        float Sr = 0.f, Si = 0.f;
#pragma unroll
        for (int i = 0; i < 4; i++) {
#pragma unroll
            for (int r4 = 0; r4 < 4; r4++) {
                int m = bm * 128 + wm * 64 + i * 16 + quad * 4 + r4;
                size_t idx = (size_t)m * ld + n;
                float v = acc[i][j][r4];
                if (EPI == 1) {
                    v += b2f(bias[n]);
                    outB[idx] = f2b(v);
                    outB2[idx] = f2b(v);
                } else if (EPI == 2) {
                    v += b2f(Dv[n]) * (fstats[n] * b2f(aux[idx]) + fstats[256 + n]);
                    outB[idx] = f2b(v);
                } else if (EPI == 5) {
                    v += b2f(bias[n]) + b2f(aux[idx]);
                    outB[idx] = f2b(v);
                } else if (EPI == 6) {
                    v += fstats[n];
                    bf16 ob = f2b(v);
                    outB[idx] = ob;
                    float vr = b2f(ob);
                    float wr = Er[r4] * Cr[i] - Ei[r4] * Cim[i];
                    float wi = Er[r4] * Cim[i] + Ei[r4] * Cr[i];
                    Sr += vr * wr;
                    Si += vr * wi;
                }
                if (STATS) { ss += v; ss2 += v * v; }
            }
        }
        if constexpr (EPI == 6) {
            Sr += __shfl_xor(Sr, 16); Sr += __shfl_xor(Sr, 32);
            Si += __shfl_xor(Si, 16); Si += __shfl_xor(Si, 32);
            float pSr = __shfl_xor(Sr, 1), pSi = __shfl_xor(Si, 1);
            if (quad == 0 && (cl & 1) == 0) {
                size_t gc = (size_t)(bm * 2 + wm);      // global time-chunk
                size_t ci = (gc * 256 + (size_t)(n >> 1)) * 2;
                carry[ci]     = Sr - pSi;
                carry[ci + 1] = Si + pSr;
            }
        }
        if (STATS) {
            ss += __shfl_xor(ss, 16);  ss += __shfl_xor(ss, 32);
            ss2 += __shfl_xor(ss2, 16); ss2 += __shfl_xor(ss2, 32);
            if (lane < 16) {
                int nl = wn * 32 + j * 16 + lane;
                sred[wm * 64 + nl] = ss;
                sred[128 + wm * 64 + nl] = ss2;
            }
        }
    }
    if constexpr (STATS) {
        __syncthreads();
        if (tid < 64) {
            float sv = sred[tid] + sred[64 + tid];
            float sv2 = sred[128 + tid] + sred[192 + tid];
            spart[(size_t)bm * 256 + bn * 64 + tid] = sv;
            spart[131072 + (size_t)bm * 256 + bn * 64 + tid] = sv2;
        }
    }
}

// ---------------- fused GLU: TWO 128m x (64v+64g) tiles per block --------
// 4 waves each 64m x (32v+32g). 3-buffer ring 48KB, single barrier per
// step. Steady vmcnt(4); G in {8,9} -> vmcnt(20) (the tile-0 epilogue's
// 16 stores sit between stage(G) and the wait point; vmcnt retires
// oldest-first so 20 = 4 + 16 younger ops still guarantees stage(G)
// retired); tail -> vmcnt(0).
__global__ __launch_bounds__(256)
void glu_v8(const bf16* __restrict__ A, const bf16* __restrict__ W,
            bf16* __restrict__ outB, const bf16* __restrict__ bias)
{
    constexpr int KK = 256;
    constexpr int GT = 16;
    const int id = blockIdx.x;
    const int xcd = id & 7, q = id >> 3;
    const int nb = q & 7;
    const int mgrp = (q >> 3) * 8 + xcd;       // 0..255

    const int tid = threadIdx.x;
    const int lane = tid & 63, wv = tid >> 6;
    const int wm = wv >> 1, wn = wv & 1;
    const int quad = lane >> 4, cl = lane & 15;

    __shared__ __align__(16) short As[3][128 * 32];
    __shared__ __align__(16) short Vs[3][64 * 32];
    __shared__ __align__(16) short Gs[3][64 * 32];

    const char* Abase = (const char*)A;
    const char* Vb = (const char*)W + (size_t)(nb * 64) * ((size_t)KK * 2);
    const char* Gb = (const char*)W + (size_t)(512 + nb * 64) * ((size_t)KK * 2);
    constexpr int ldb = KK * 2;

    auto stage = [&](int G) {
        const int tile = G >> 3;
        const int kb = (G & 7) * 64;
        const int bi = G % 3;
        const char* Ab = Abase + (size_t)(mgrp * 2 + tile) * 128 * ((size_t)KK * 2);
#pragma unroll
        for (int it = 0; it < 2; ++it) {
            int Gt = it * 256 + tid;
            int r = Gt >> 2;
            int gl = (Gt & 3) ^ ((r >> 1) & 3);
            ld_g2l(Ab + (size_t)r * ldb + kb + gl * 16,
                   (char*)As[bi] + (it * 4 + wv) * 1024);
        }
        {
            int r = tid >> 2;
            int gl = (tid & 3) ^ ((r >> 1) & 3);
            ld_g2l(Vb + (size_t)r * ldb + kb + gl * 16, (char*)Vs[bi] + wv * 1024);
            ld_g2l(Gb + (size_t)r * ldb + kb + gl * 16, (char*)Gs[bi] + wv * 1024);
        }
    };

    f4v accv[4][2], accg[4][2];
#pragma unroll
    for (int i = 0; i < 4; i++)
#pragma unroll
        for (int j = 0; j < 2; j++) {
            accv[i][j] = (f4v){0.f, 0.f, 0.f, 0.f};
            accg[i][j] = (f4v){0.f, 0.f, 0.f, 0.f};
        }

    stage(0);
    stage(1);
#pragma unroll
    for (int G = 0; G < GT; ++G) {
        if (G == 8 || G == 9) {
            asm volatile("s_waitcnt vmcnt(20)" ::: "memory");
        } else if (G + 1 < GT) {
            asm volatile("s_waitcnt vmcnt(4)" ::: "memory");
        } else {
            asm volatile("s_waitcnt vmcnt(0)" ::: "memory");
        }
        asm volatile("s_barrier" ::: "memory");
        if (G + 2 < GT) stage(G + 2);
        const char* Ac = (const char*)As[G % 3];
        const char* Vc = (const char*)Vs[G % 3];
        const char* Gc = (const char*)Gs[G % 3];
        s8v af[4], bv[2], bg[2];
#pragma unroll
        for (int i = 0; i < 4; i++) {
            int r = wm * 64 + i * 16 + cl;
            af[i] = *(const s8v*)(Ac + r * 64 + ((quad ^ ((r >> 1) & 3)) * 16));
        }
#pragma unroll
        for (int j = 0; j < 2; j++) {
            int r = wn * 32 + j * 16 + cl;
            int off = r * 64 + ((quad ^ ((r >> 1) & 3)) * 16);
            bv[j] = *(const s8v*)(Vc + off);
            bg[j] = *(const s8v*)(Gc + off);
        }
#pragma unroll
        for (int i = 0; i < 4; i++)
#pragma unroll
            for (int j = 0; j < 2; j++) {
                accv[i][j] = __builtin_amdgcn_mfma_f32_16x16x32_bf16(af[i], bv[j], accv[i][j], 0, 0, 0);
                accg[i][j] = __builtin_amdgcn_mfma_f32_16x16x32_bf16(af[i], bg[j], accg[i][j], 0, 0, 0);
            }

        if ((G & 7) == 7) {
            const int bm = mgrp * 2 + (G >> 3);
#pragma unroll
            for (int i = 0; i < 4; i++) {
#pragma unroll
                for (int j = 0; j < 2; j++) {
#pragma unroll
                    for (int r4 = 0; r4 < 4; r4++) {
                        int m = bm * 128 + wm * 64 + i * 16 + quad * 4 + r4;
                        int n = nb * 64 + wn * 32 + j * 16 + cl;
                        float v = accv[i][j][r4] + b2f(bias[n]);
                        float g = accg[i][j][r4] + b2f(bias[512 + n]);
                        outB[(size_t)m * 512 + n] = f2b(v * (1.f / (1.f + __expf(-g))));
                    }
                }
            }
            if (G + 1 < GT) {
#pragma unroll
                for (int i = 0; i < 4; i++)
#pragma unroll
                    for (int j = 0; j < 2; j++) {
                        accv[i][j] = (f4v){0.f, 0.f, 0.f, 0.f};
                        accg[i][j] = (f4v){0.f, 0.f, 0.f, 0.f};
                    }
            }
        }
    }
}

// ---------------- BatchNorm finish: partials -> affine tables -------------
__global__ void bn_finish2(const float* __restrict__ part, float* __restrict__ stats,
                           const bf16* __restrict__ sc, const bf16* __restrict__ bi) {
    int e = blockIdx.x;   // 256
    int t = threadIdx.x;
    float s = part[(size_t)t * 256 + e] + part[(size_t)(t + 256) * 256 + e];
    float s2 = part[131072 + (size_t)t * 256 + e] + part[131072 + (size_t)(t + 256) * 256 + e];
    __shared__ float rs[256], rs2[256];
    rs[t] = s; rs2[t] = s2;
    __syncthreads();
    for (int k = 128; k > 0; k >>= 1) {
        if (t < k) { rs[t] += rs[t + k]; rs2[t] += rs2[t + k]; }
        __syncthreads();
    }
    if (t == 0) {
        float mu = rs[0] * (1.f / 65536.f);
        float var = rs2[0] * (1.f / 65536.f) - mu * mu;
        float a = rsqrtf(var + 1e-5f) * b2f(sc[e]);
        stats[e] = a;
        stats[256 + e] = b2f(bi[e]) - mu * a;
    }
}

// wb[n,e] = B_?[h,e]*gamma[h]*a[e] with INTERLEAVED rows (n=2h -> re, 2h+1 -> im)
// + fused Bu bias: bubias[n] = gamma[h] * sum_e c[e]*B_?[h,e]
__global__ void pack_wb(const void* __restrict__ B_re, const void* __restrict__ B_im,
                        size_t off, const float* __restrict__ gam,
                        const float* __restrict__ stats,
                        bf16* __restrict__ out, float* __restrict__ bias_out,
                        const int* __restrict__ flag) {
    int f = *flag;
    int n = blockIdx.x;   // 512
    int e = threadIdx.x;
    int h = n >> 1;
    const void* src = (n & 1) ? B_im : B_re;
    float v = ldf(src, off + (size_t)h * 256 + e, f);
    out[(size_t)n * 256 + e] = f2b(v * gam[h] * stats[e]);
    __shared__ float rs[256];
    rs[e] = v * stats[256 + e];
    __syncthreads();
    for (int k = 128; k > 0; k >>= 1) {
        if (e < k) rs[e] += rs[e + k];
        __syncthreads();
    }
    if (e == 0) bias_out[n] = rs[0] * gam[h];
}

// all-layer weight packing up front: 6 layers x (wc 512 + w1t 1024 + w2t 512)
__global__ void pack_all(const void* __restrict__ C_re, const void* __restrict__ C_im,
                         const void* __restrict__ W1, const void* __restrict__ W2,
                         bf16* __restrict__ wc6, bf16* __restrict__ w1t6, bf16* __restrict__ w2t6,
                         const int* __restrict__ flag) {
    int f = *flag;
    int L = blockIdx.x >> 11;          // /2048
    int blk = blockIdx.x & 2047;
    size_t offC = (size_t)L * 65536, offW1 = (size_t)L * 262144, offW2 = (size_t)L * 131072;
    if (blk < 512) {
        // wc rows (k interleaved): k=2h -> C_re[e,h], k=2h+1 -> -C_im[e,h]
        int g = blk * 256 + threadIdx.x;
        int e = g >> 9, k = g & 511, h = k >> 1;
        float v = ldf((k & 1) ? C_im : C_re, offC + (size_t)e * 256 + h, f);
        wc6[(size_t)L * 131072 + g] = f2b((k & 1) ? -v : v);
    } else if (blk < 1536) {
        int g = (blk - 512) * 256 + threadIdx.x;
        int n = g >> 8, k = g & 255;
        w1t6[(size_t)L * 262144 + g] = f2b(ldf(W1, offW1 + (size_t)k * 1024 + n, f));
    } else {
        int g = (blk - 1536) * 256 + threadIdx.x;
        int n = g >> 9, k = g & 511;
        w2t6[(size_t)L * 131072 + g] = f2b(ldf(W2, offW2 + (size_t)k * 256 + n, f));
    }
}

// ---------------- LRU final: fused chunk-prefix + in-place scan ----------
// carry produced by the Bu GEMM epilogue (EPI 6). Each thread first builds
// its chunk's prefix (er = lam^64 * er + carry[c'], c' < c — wave-uniform
// trip count; carry is 2MB L2-resident, 16B/iter), then scans its 64 rows.
__global__ void lru_final(bf16* __restrict__ bu, const float* __restrict__ carry,
                          const float* __restrict__ lam) {
    int gg = blockIdx.x * 256 + threadIdx.x;  // 131072
    int hp = gg & 127, c = (gg >> 7) & 31, b = gg >> 12;
    f4v lm = *(const f4v*)&lam[hp * 4];
    // lam^64 for both h of the pair (6 squarings)
    float q0r = lm[0], q0i = lm[1], q1r = lm[2], q1i = lm[3];
#pragma unroll
    for (int k = 0; k < 6; k++) {
        float n0 = q0r * q0r - q0i * q0i; q0i = 2.f * q0r * q0i; q0r = n0;
        float n1 = q1r * q1r - q1i * q1i; q1i = 2.f * q1r * q1i; q1r = n1;
    }
    float sr0 = 0.f, si0 = 0.f, sr1 = 0.f, si1 = 0.f;
    const f4v* cp = (const f4v*)(carry + ((size_t)b * 32) * 512) + hp;
    for (int cc = 0; cc < c; cc++) {
        f4v cv = *cp;
        float n0 = q0r * sr0 - q0i * si0 + cv[0];
        si0 = q0r * si0 + q0i * sr0 + cv[1]; sr0 = n0;
        float n1 = q1r * sr1 - q1i * si1 + cv[2];
        si1 = q1r * si1 + q1i * sr1 + cv[3]; sr1 = n1;
        cp += 128;   // next chunk (512 floats)
    }
    char* p = (char*)(bu + ((size_t)(b * TLEN + c * TCH)) * 512) + hp * 8;
    for (int t = 0; t < TCH; t++) {
        unsigned long long u = *(const unsigned long long*)p;
        float ur0 = bits2f((unsigned short)u), ui0 = bits2f((unsigned short)(u >> 16));
        float ur1 = bits2f((unsigned short)(u >> 32)), ui1 = bits2f((unsigned short)(u >> 48));
        float nr0 = lm[0] * sr0 - lm[1] * si0 + ur0;
        si0 = lm[0] * si0 + lm[1] * sr0 + ui0; sr0 = nr0;
        float nr1 = lm[2] * sr1 - lm[3] * si1 + ur1;
        si1 = lm[2] * si1 + lm[3] * sr1 + ui1; sr1 = nr1;
        unsigned long long w = (unsigned long long)f2bits(sr0)
                             | ((unsigned long long)f2bits(si0) << 16)
                             | ((unsigned long long)f2bits(sr1) << 32)
                             | ((unsigned long long)f2bits(si1) << 48);
        *(unsigned long long*)p = w;
        p += 1024;
    }
}

// ---------------- head (pool partials come from the last W2's BN-stats) ---
__global__ void head_k(const float* __restrict__ part, const bf16* __restrict__ W_out,
                       const bf16* __restrict__ b_out, void* __restrict__ out,
                       const int* __restrict__ flag) {
    int b = blockIdx.x;
    int tid = threadIdx.x;
    __shared__ float sp[256];
    __shared__ float red[160];
    float s = 0.f;
    for (int c = 0; c < 16; c++) s += part[((size_t)(b * 16 + c)) * 256 + tid];
    sp[tid] = s * (1.f / 2048.f);
    __syncthreads();
    if (tid < 160) {
        int o = tid >> 4, sg = tid & 15;
        float a = 0.f;
        for (int e = sg; e < 256; e += 16) a += sp[e] * b2f(W_out[e * 10 + o]);
        red[tid] = a;
    }
    __syncthreads();
    if (tid < 10) {
        float acc = b2f(b_out[tid]);
        for (int sg = 0; sg < 16; sg++) acc += red[tid * 16 + sg];
        if (*flag) ((float*)out)[b * 10 + tid] = acc;
        else       ((bf16*)out)[b * 10 + tid] = f2b(acc);
    }
}

__global__ void pack_wt_enc(const void* __restrict__ W_enc, bf16* __restrict__ out,
                            const int* __restrict__ flag) {
    int f = *flag;
    int g = blockIdx.x * 256 + threadIdx.x;  // 16384
    int n = g >> 6, k = g & 63;
    out[g] = f2b(ldf(W_enc, (size_t)k * 256 + n, f));
}

extern "C" void kernel_launch(void* const* d_in, const int* in_sizes, int n_in,
                              void* d_out, int out_size, void* d_ws, size_t ws_size,
                              hipStream_t stream) {
    (void)in_sizes; (void)n_in; (void)out_size; (void)ws_size;
    const void* x      = d_in[0];
    const void* W_enc  = d_in[1];
    const void* b_enc  = d_in[2];
    const void* nu_log = d_in[3];
    const void* th_log = d_in[4];
    const void* B_re   = d_in[5];
    const void* B_im   = d_in[6];
    const void* C_re   = d_in[7];
    const void* C_im   = d_in[8];
    const void* Dp     = d_in[9];
    const void* W1     = d_in[10];
    const void* b1     = d_in[11];
    const void* W2     = d_in[12];
    const void* b2     = d_in[13];
    const void* bn_s   = d_in[14];
    const void* bn_b   = d_in[15];
    const void* W_out  = d_in[16];
    const void* b_out  = d_in[17];

    // workspace layout (~178 MB)
    char* w = (char*)d_ws;
    bf16* xc  = (bf16*)w; w += (size_t)MTOT * 256 * 2;   // residual stream
    bf16* y   = (bf16*)w; w += (size_t)MTOT * 256 * 2;   // residual anchor
    bf16* hbn = (bf16*)w; w += (size_t)MTOT * 256 * 2;   // LRU out
    bf16* bu  = (bf16*)w; w += (size_t)MTOT * 512 * 2;   // Bu/hs (interleaved), GLU out
    float* stats  = (float*)w; w += 4096;                // a[256], c[256]
    float* bnpart = (float*)w; w += 1048576;             // stats partials (also pool partials)
    float* carry  = (float*)w; w += 2097152;             // 1024 chunks x 256 h x 2 fp32
    float* lamb   = (float*)w; w += 12288;               // 1536*2 fp32
    float* gamt   = (float*)w; w += 6144;                // 1536 fp32
    float* bubias = (float*)w; w += 2048;                // 512 fp32
    int*   flag   = (int*)w;  w += 256;
    bf16* wt_enc = (bf16*)w; w += 32768;
    bf16* wb   = (bf16*)w; w += 262144;
    bf16* wc6  = (bf16*)w; w += 6 * 262144;              // 1.57 MB
    bf16* w1t6 = (bf16*)w; w += 6 * 524288;              // 3.15 MB
    bf16* w2t6 = (bf16*)w; w += 6 * 262144;              // 1.57 MB
    bf16* b_encb = (bf16*)w; w += 512;
    bf16* Db     = (bf16*)w; w += 3072;
    bf16* b1b    = (bf16*)w; w += 12288;
    bf16* b2b    = (bf16*)w; w += 3072;
    bf16* bnsb   = (bf16*)w; w += 3072;
    bf16* bnbb   = (bf16*)w; w += 3072;
    bf16* Woutb  = (bf16*)w; w += 5120;
    bf16* boutb  = (bf16*)w; w += 32;
    bf16* xb = bu;  // x's bf16 copy aliases bu (dead until first Bu GEMM)

    dim3 blk(256);
    detect_k<<<1, blk, 0, stream>>>((const unsigned short*)x, flag);
    cvt_k4<<<4096, blk, 0, stream>>>(x, xb, 4194304, flag);
    cvt_small<<<60, blk, 0, stream>>>(b_enc, Dp, b1, b2, bn_s, bn_b, W_out, b_out,
                                      b_encb, Db, b1b, b2b, bnsb, bnbb, Woutb, boutb, flag);
    lamgam_k<<<6, blk, 0, stream>>>(nu_log, th_log, lamb, gamt, flag);
    pack_wt_enc<<<64, blk, 0, stream>>>(W_enc, wt_enc, flag);
    pack_all<<<12288, blk, 0, stream>>>(C_re, C_im, W1, W2, wc6, w1t6, w2t6, flag);

    // encoder: [M,64] @ W_enc^T + b_enc -> xc and y (+ BN stats partials)
    gemm_v7<64, 4, 1><<<2048, blk, 0, stream>>>(xb, wt_enc, xc, y, 256,
                                                b_encb, nullptr, nullptr, nullptr, bnpart,
                                                nullptr, nullptr);
    for (int i = 0; i < 6; ++i) {
        bn_finish2<<<256, blk, 0, stream>>>(bnpart, stats, bnsb + i * 256, bnbb + i * 256);
        pack_wb<<<512, blk, 0, stream>>>(B_re, B_im, (size_t)i * 65536, gamt + i * 256,
                                         stats, wb, bubias, flag);
        // Bu = BN(xc) @ (gamma*[B;B])^T -> bu [M,512] + fused chunk-carry
        gemm_v7<256, 8, 6><<<4096, blk, 0, stream>>>(xc, wb, bu, nullptr, 512,
                                                     nullptr, nullptr, nullptr, bubias, nullptr,
                                                     lamb + i * 512, carry);
        // scan (prefix fused): bu <- hs in place
        lru_final<<<512, blk, 0, stream>>>(bu, carry, lamb + i * 512);
        // lru_out = hs @ [C_re;-C_im]^T + D*(a*xc+c) -> hbn [M,256]
        gemm_v7<512, 4, 2><<<2048, blk, 0, stream>>>(bu, wc6 + (size_t)i * 131072, hbn, nullptr, 256,
                                                     nullptr, Db + i * 256, xc, stats, nullptr,
                                                     nullptr, nullptr);
        // fused GLU MLP: bu = (hbn@W1v+b1v)*sigmoid(hbn@W1g+b1g)  [M,512]
        glu_v8<<<2048, blk, 0, stream>>>(hbn, w1t6 + (size_t)i * 262144, bu, b1b + i * 1024);
        // xc = glu @ W2^T + b2 + y (+ BN stats / pool partials for next stage)
        gemm_v7<512, 4, 5><<<2048, blk, 0, stream>>>(bu, w2t6 + (size_t)i * 131072, xc, nullptr, 256,
                                                     b2b + i * 256, nullptr, y, nullptr, bnpart,
                                                     nullptr, nullptr);
    }
    head_k<<<32, blk, 0, stream>>>(bnpart, Woutb, boutb, d_out, flag);
}

// Round 12
// 1390.219 us; speedup vs baseline: 1.0336x; 1.0336x over previous
//
#include <hip/hip_runtime.h>
#include <hip/hip_bf16.h>
#include <math.h>

using bf16 = __hip_bfloat16;
typedef __attribute__((ext_vector_type(8))) short s8v;
typedef __attribute__((ext_vector_type(4))) float f4v;

#define MTOT 65536   // B*T
#define TLEN 2048
#define NCHUNK 32
#define TCH 64

__device__ __forceinline__ float b2f(bf16 x) { return __bfloat162float(x); }
__device__ __forceinline__ bf16 f2b(float x) { return __float2bfloat16(x); }
__device__ __forceinline__ float bits2f(unsigned short u) {
    unsigned int x = ((unsigned int)u) << 16; float f; __builtin_memcpy(&f, &x, 4); return f;
}
__device__ __forceinline__ unsigned short f2bits(float x) {
    bf16 h = f2b(x); unsigned short u; __builtin_memcpy(&u, &h, 2); return u;
}

// flagged load: f32 buffer if f!=0 else bf16 buffer
__device__ __forceinline__ float ldf(const void* p, size_t i, int f) {
    return f ? ((const float*)p)[i] : b2f(((const bf16*)p)[i]);
}

__device__ __forceinline__ void ld_g2l(const void* g, void* l) {
    __builtin_amdgcn_global_load_lds(
        (const __attribute__((address_space(1))) void*)g,
        (__attribute__((address_space(3))) void*)l,
        16, 0, 0);
}

// ---------------- dtype detection ----------------
__global__ void detect_k(const unsigned short* __restrict__ x, int* __restrict__ flag) {
    int tid = threadIdx.x;
    int cnt = 0;
    for (int i = tid; i < 8192; i += 256) {
        int e = (x[i] >> 7) & 0xFF;
        if (e == 0 || e == 0xFF) cnt++;
    }
    __shared__ int red[256];
    red[tid] = cnt;
    __syncthreads();
    for (int s = 128; s > 0; s >>= 1) {
        if (tid < s) red[tid] += red[tid + s];
        __syncthreads();
    }
    if (tid == 0) flag[0] = (red[0] >= 2) ? 1 : 0;
}

// x4-vectorized convert
__global__ void cvt_k4(const void* __restrict__ src, bf16* __restrict__ dst, int n,
                       const int* __restrict__ flag) {
    int f = *flag;
    int i = (blockIdx.x * 256 + threadIdx.x) * 4;
    if (i + 3 < n) {
#pragma unroll
        for (int k = 0; k < 4; k++) dst[i + k] = f2b(ldf(src, i + k, f));
    } else {
        for (int k = 0; k < 4 && i + k < n; k++) dst[i + k] = f2b(ldf(src, i + k, f));
    }
}

// merged small-tensor converts (60 blocks)
__global__ void cvt_small(const void* b_enc, const void* Dp, const void* b1, const void* b2,
                          const void* bn_s, const void* bn_b, const void* W_out, const void* b_out,
                          bf16* b_encb, bf16* Db, bf16* b1b, bf16* b2b, bf16* bnsb, bf16* bnbb,
                          bf16* Woutb, bf16* boutb, const int* __restrict__ flag) {
    int f = *flag;
    int blk = blockIdx.x, t = threadIdx.x;
    const void* src; bf16* dst; int base, n;
    if (blk < 1)       { src = b_enc; dst = b_encb; base = blk;      n = 256; }
    else if (blk < 7)  { src = Dp;    dst = Db;     base = blk - 1;  n = 1536; }
    else if (blk < 31) { src = b1;    dst = b1b;    base = blk - 7;  n = 6144; }
    else if (blk < 37) { src = b2;    dst = b2b;    base = blk - 31; n = 1536; }
    else if (blk < 43) { src = bn_s;  dst = bnsb;   base = blk - 37; n = 1536; }
    else if (blk < 49) { src = bn_b;  dst = bnbb;   base = blk - 43; n = 1536; }
    else if (blk < 59) { src = W_out; dst = Woutb;  base = blk - 49; n = 2560; }
    else               { src = b_out; dst = boutb;  base = 0;        n = 10; }
    int i = base * 256 + t;
    if (i < n) dst[i] = f2b(ldf(src, i, f));
}

__global__ void lamgam_k(const void* __restrict__ nu, const void* __restrict__ th,
                         float* __restrict__ lamb, float* __restrict__ gamt,
                         const int* __restrict__ flag) {
    int f = *flag;
    int g = blockIdx.x * 256 + threadIdx.x;  // 1536
    float nl = ldf(nu, g, f), tl = ldf(th, g, f);
    float mag = expf(-expf(nl));
    float ang = expf(tl);
    lamb[g * 2] = mag * cosf(ang);
    lamb[g * 2 + 1] = mag * sinf(ang);
    gamt[g] = sqrtf(fmaxf(1.f - mag * mag, 1e-12f));
}

// =====================================================================
// GEMM out[m,n] = sum_k A[m,k]*W[n,k] (+epilogue). 128m x 64n tile,
// 4 waves (each 64x32), BK=32, 3-buffer LDS ring (36KB), depth-2
// prefetch with counted vmcnt(6) (3 reqs/thread/stage), tails 3 -> 0.
// Two barriers per K-step (verified optimum; single-barrier variant
// regressed in r11 — shortened effective prefetch distance).
// NBN column-siblings of an M-tile land on the same XCD (L2 A reuse).
// EPI 1: +bias -> outB & outB2, + BN-stats partials      (encoder)
// EPI 2: +Dv[n]*(a[n]*aux+c[n]) -> bf16                  (LRU C-out)
// EPI 5: v+bias+aux[m,n] -> bf16, + BN-stats partials    (W2 + residual;
//        the sum-partial doubles as the pooling partial for the head)
// EPI 6: +fbias[n] (fp32) -> bf16, + FUSED LRU CHUNK CARRY (r9 notes)
// =====================================================================
template<int KK, int NBN, int EPI>
__global__ __launch_bounds__(256)
void gemm_v7(const bf16* __restrict__ A, const bf16* __restrict__ W,
             bf16* __restrict__ outB, bf16* __restrict__ outB2, int ldo,
             const bf16* __restrict__ bias,
             const bf16* __restrict__ Dv, const bf16* __restrict__ aux,
             const float* __restrict__ fstats, float* __restrict__ spart,
             const float* __restrict__ lamp, float* __restrict__ carry)
{
    constexpr int LG = (NBN == 8) ? 3 : 2;
    const int id = blockIdx.x;
    const int xcd = id & 7, q = id >> 3;
    const int bn = q & (NBN - 1);
    const int bm = (q >> LG) * 8 + xcd;

    const int tid = threadIdx.x;
    const int lane = tid & 63, wv = tid >> 6;
    const int wm = wv >> 1, wn = wv & 1;
    const int quad = lane >> 4, cl = lane & 15;

    __shared__ __align__(16) short As[3][128 * 32];
    __shared__ __align__(16) short Ws[3][64 * 32];
    __shared__ float sred[256];

    const char* Ab = (const char*)A + (size_t)bm * 128 * ((size_t)KK * 2);
    const char* Wb = (const char*)W + (size_t)bn * 64 * ((size_t)KK * 2);
    constexpr int ldb = KK * 2;

    auto stage = [&](int t, int bi) {
        const int kb = t * 64;
#pragma unroll
        for (int it = 0; it < 2; ++it) {
            int G = it * 256 + tid;
            int r = G >> 2;
            int gl = (G & 3) ^ ((r >> 1) & 3);
            ld_g2l(Ab + (size_t)r * ldb + kb + gl * 16,
                   (char*)As[bi] + (it * 4 + wv) * 1024);
        }
        {
            int r = tid >> 2;
            int gl = (tid & 3) ^ ((r >> 1) & 3);
            ld_g2l(Wb + (size_t)r * ldb + kb + gl * 16,
                   (char*)Ws[bi] + wv * 1024);
        }
    };

    f4v acc[4][2];
#pragma unroll
    for (int i = 0; i < 4; i++)
#pragma unroll
        for (int j = 0; j < 2; j++) acc[i][j] = (f4v){0.f, 0.f, 0.f, 0.f};

    constexpr int NT = KK >> 5;
    stage(0, 0);
    if (NT > 1) stage(1, 1);
#pragma unroll
    for (int t = 0; t < NT; ++t) {
        if (t + 2 < NT) {
            stage(t + 2, (t + 2) % 3);
            asm volatile("s_waitcnt vmcnt(6)" ::: "memory");
        } else if (t + 1 < NT) {
            asm volatile("s_waitcnt vmcnt(3)" ::: "memory");
        } else {
            asm volatile("s_waitcnt vmcnt(0)" ::: "memory");
        }
        asm volatile("s_barrier" ::: "memory");
        const char* Ac = (const char*)As[t % 3];
        const char* Wc = (const char*)Ws[t % 3];
        s8v af[4], bw[2];
#pragma unroll
        for (int i = 0; i < 4; i++) {
            int r = wm * 64 + i * 16 + cl;
            af[i] = *(const s8v*)(Ac + r * 64 + ((quad ^ ((r >> 1) & 3)) * 16));
        }
#pragma unroll
        for (int j = 0; j < 2; j++) {
            int r = wn * 32 + j * 16 + cl;
            bw[j] = *(const s8v*)(Wc + r * 64 + ((quad ^ ((r >> 1) & 3)) * 16));
        }
#pragma unroll
        for (int i = 0; i < 4; i++)
#pragma unroll
            for (int j = 0; j < 2; j++)
                acc[i][j] = __builtin_amdgcn_mfma_f32_16x16x32_bf16(af[i], bw[j], acc[i][j], 0, 0, 0);
        asm volatile("s_barrier" ::: "memory");
    }

    const size_t ld = (size_t)ldo;
    constexpr bool STATS = (EPI == 1 || EPI == 5);
#pragma unroll
    for (int j = 0; j < 2; j++) {
        float ss = 0.f, ss2 = 0.f;
        const int n = bn * 64 + wn * 32 + j * 16 + cl;
        // ---- carry-weight tables (EPI 6 only) ----
        float Er[4], Ei[4], Cr[4], Cim[4];
        if constexpr (EPI == 6) {
            int h = n >> 1;
            float lr = lamp[h * 2], li = lamp[h * 2 + 1];
            float a2r = lr * lr - li * li, a2i = 2.f * lr * li;          // lam^2
            float a3r = a2r * lr - a2i * li, a3i = a2r * li + a2i * lr;  // lam^3
            float l4r = a2r * a2r - a2i * a2i, l4i = 2.f * a2r * a2i;    // lam^4
            float l8r = l4r * l4r - l4i * l4i, l8i = 2.f * l4r * l4i;
            float l12r = l8r * l4r - l8i * l4i, l12i = l8r * l4i + l8i * l4r;
            float Br = (quad == 0) ? l12r : (quad == 1) ? l8r : (quad == 2) ? l4r : 1.f;
            float Bi = (quad == 0) ? l12i : (quad == 1) ? l8i : (quad == 2) ? l4i : 0.f;
            float Ar[4] = { a3r, a2r, lr, 1.f };
            float Ai[4] = { a3i, a2i, li, 0.f };
#pragma unroll
            for (int r4 = 0; r4 < 4; r4++) {
                Er[r4] = Ar[r4] * Br - Ai[r4] * Bi;
                Ei[r4] = Ar[r4] * Bi + Ai[r4] * Br;
            }
            float l16r = l12r * l4r - l12i * l4i, l16i = l12r * l4i + l12i * l4r;
            float l32r = l16r * l16r - l16i * l16i, l32i = 2.f * l16r * l16i;
            float l48r = l32r * l16r - l32i * l16i, l48i = l32r * l16i + l32i * l16r;
            Cr[0] = l48r; Cim[0] = l48i;   // i=0 -> lam^48
            Cr[1] = l32r; Cim[1] = l32i;
            Cr[2] = l16r; Cim[2] = l16i;
            Cr[3] = 1.f;  Cim[3] = 0.f;
        }
        float Sr = 0.f, Si = 0.f;
#pragma unroll
        for (int i = 0; i < 4; i++) {
#pragma unroll
            for (int r4 = 0; r4 < 4; r4++) {
                int m = bm * 128 + wm * 64 + i * 16 + quad * 4 + r4;
                size_t idx = (size_t)m * ld + n;
                float v = acc[i][j][r4];
                if (EPI == 1) {
                    v += b2f(bias[n]);
                    outB[idx] = f2b(v);
                    outB2[idx] = f2b(v);
                } else if (EPI == 2) {
                    v += b2f(Dv[n]) * (fstats[n] * b2f(aux[idx]) + fstats[256 + n]);
                    outB[idx] = f2b(v);
                } else if (EPI == 5) {
                    v += b2f(bias[n]) + b2f(aux[idx]);
                    outB[idx] = f2b(v);
                } else if (EPI == 6) {
                    v += fstats[n];
                    bf16 ob = f2b(v);
                    outB[idx] = ob;
                    float vr = b2f(ob);
                    float wr = Er[r4] * Cr[i] - Ei[r4] * Cim[i];
                    float wi = Er[r4] * Cim[i] + Ei[r4] * Cr[i];
                    Sr += vr * wr;
                    Si += vr * wi;
                }
                if (STATS) { ss += v; ss2 += v * v; }
            }
        }
        if constexpr (EPI == 6) {
            Sr += __shfl_xor(Sr, 16); Sr += __shfl_xor(Sr, 32);
            Si += __shfl_xor(Si, 16); Si += __shfl_xor(Si, 32);
            float pSr = __shfl_xor(Sr, 1), pSi = __shfl_xor(Si, 1);
            if (quad == 0 && (cl & 1) == 0) {
                size_t gc = (size_t)(bm * 2 + wm);      // global time-chunk
                size_t ci = (gc * 256 + (size_t)(n >> 1)) * 2;
                carry[ci]     = Sr - pSi;
                carry[ci + 1] = Si + pSr;
            }
        }
        if (STATS) {
            ss += __shfl_xor(ss, 16);  ss += __shfl_xor(ss, 32);
            ss2 += __shfl_xor(ss2, 16); ss2 += __shfl_xor(ss2, 32);
            if (lane < 16) {
                int nl = wn * 32 + j * 16 + lane;
                sred[wm * 64 + nl] = ss;
                sred[128 + wm * 64 + nl] = ss2;
            }
        }
    }
    if constexpr (STATS) {
        __syncthreads();
        if (tid < 64) {
            float sv = sred[tid] + sred[64 + tid];
            float sv2 = sred[128 + tid] + sred[192 + tid];
            spart[(size_t)bm * 256 + bn * 64 + tid] = sv;
            spart[131072 + (size_t)bm * 256 + bn * 64 + tid] = sv2;
        }
    }
}

// ---------------- fused GLU: TWO 128m x (64v+64g) tiles per block --------
// 4 waves each 64m x (32v+32g). 3-buffer ring 48KB; ring runs continuously
// across the tile boundary (one pipeline fill per block). The tile-0
// epilogue issues 32 stores/thread between stage(9) and stage(10), so at
// G in {8,9} the correct counted wait is vmcnt(40) (= 8 stage reqs + 32
// stores younger than the stage being protected; vmcnt retires
// oldest-first) — the old vmcnt(8) force-drained all 32 stores there.
__global__ __launch_bounds__(256)
void glu_v8(const bf16* __restrict__ A, const bf16* __restrict__ W,
            bf16* __restrict__ outB, const bf16* __restrict__ bias)
{
    constexpr int KK = 256;
    constexpr int GT = 16;
    const int id = blockIdx.x;
    const int xcd = id & 7, q = id >> 3;
    const int nb = q & 7;
    const int mgrp = (q >> 3) * 8 + xcd;       // 0..255

    const int tid = threadIdx.x;
    const int lane = tid & 63, wv = tid >> 6;
    const int wm = wv >> 1, wn = wv & 1;
    const int quad = lane >> 4, cl = lane & 15;

    __shared__ __align__(16) short As[3][128 * 32];
    __shared__ __align__(16) short Vs[3][64 * 32];
    __shared__ __align__(16) short Gs[3][64 * 32];

    const char* Abase = (const char*)A;
    const char* Vb = (const char*)W + (size_t)(nb * 64) * ((size_t)KK * 2);
    const char* Gb = (const char*)W + (size_t)(512 + nb * 64) * ((size_t)KK * 2);
    constexpr int ldb = KK * 2;

    auto stage = [&](int G) {
        const int tile = G >> 3;
        const int kb = (G & 7) * 64;
        const int bi = G % 3;
        const char* Ab = Abase + (size_t)(mgrp * 2 + tile) * 128 * ((size_t)KK * 2);
#pragma unroll
        for (int it = 0; it < 2; ++it) {
            int Gt = it * 256 + tid;
            int r = Gt >> 2;
            int gl = (Gt & 3) ^ ((r >> 1) & 3);
            ld_g2l(Ab + (size_t)r * ldb + kb + gl * 16,
                   (char*)As[bi] + (it * 4 + wv) * 1024);
        }
        {
            int r = tid >> 2;
            int gl = (tid & 3) ^ ((r >> 1) & 3);
            ld_g2l(Vb + (size_t)r * ldb + kb + gl * 16, (char*)Vs[bi] + wv * 1024);
            ld_g2l(Gb + (size_t)r * ldb + kb + gl * 16, (char*)Gs[bi] + wv * 1024);
        }
    };

    f4v accv[4][2], accg[4][2];
#pragma unroll
    for (int i = 0; i < 4; i++)
#pragma unroll
        for (int j = 0; j < 2; j++) {
            accv[i][j] = (f4v){0.f, 0.f, 0.f, 0.f};
            accg[i][j] = (f4v){0.f, 0.f, 0.f, 0.f};
        }

    stage(0);
    stage(1);
#pragma unroll
    for (int G = 0; G < GT; ++G) {
        if (G + 2 < GT) {
            stage(G + 2);
            if (G == 8 || G == 9) {
                asm volatile("s_waitcnt vmcnt(40)" ::: "memory");
            } else {
                asm volatile("s_waitcnt vmcnt(8)" ::: "memory");
            }
        } else if (G + 1 < GT) {
            asm volatile("s_waitcnt vmcnt(4)" ::: "memory");
        } else {
            asm volatile("s_waitcnt vmcnt(0)" ::: "memory");
        }
        asm volatile("s_barrier" ::: "memory");
        const char* Ac = (const char*)As[G % 3];
        const char* Vc = (const char*)Vs[G % 3];
        const char* Gc = (const char*)Gs[G % 3];
        s8v af[4], bv[2], bg[2];
#pragma unroll
        for (int i = 0; i < 4; i++) {
            int r = wm * 64 + i * 16 + cl;
            af[i] = *(const s8v*)(Ac + r * 64 + ((quad ^ ((r >> 1) & 3)) * 16));
        }
#pragma unroll
        for (int j = 0; j < 2; j++) {
            int r = wn * 32 + j * 16 + cl;
            int off = r * 64 + ((quad ^ ((r >> 1) & 3)) * 16);
            bv[j] = *(const s8v*)(Vc + off);
            bg[j] = *(const s8v*)(Gc + off);
        }
#pragma unroll
        for (int i = 0; i < 4; i++)
#pragma unroll
            for (int j = 0; j < 2; j++) {
                accv[i][j] = __builtin_amdgcn_mfma_f32_16x16x32_bf16(af[i], bv[j], accv[i][j], 0, 0, 0);
                accg[i][j] = __builtin_amdgcn_mfma_f32_16x16x32_bf16(af[i], bg[j], accg[i][j], 0, 0, 0);
            }
        asm volatile("s_barrier" ::: "memory");

        if ((G & 7) == 7) {
            const int bm = mgrp * 2 + (G >> 3);
#pragma unroll
            for (int i = 0; i < 4; i++) {
#pragma unroll
                for (int j = 0; j < 2; j++) {
#pragma unroll
                    for (int r4 = 0; r4 < 4; r4++) {
                        int m = bm * 128 + wm * 64 + i * 16 + quad * 4 + r4;
                        int n = nb * 64 + wn * 32 + j * 16 + cl;
                        float v = accv[i][j][r4] + b2f(bias[n]);
                        float g = accg[i][j][r4] + b2f(bias[512 + n]);
                        outB[(size_t)m * 512 + n] = f2b(v * (1.f / (1.f + __expf(-g))));
                    }
                }
            }
            if (G + 1 < GT) {
#pragma unroll
                for (int i = 0; i < 4; i++)
#pragma unroll
                    for (int j = 0; j < 2; j++) {
                        accv[i][j] = (f4v){0.f, 0.f, 0.f, 0.f};
                        accg[i][j] = (f4v){0.f, 0.f, 0.f, 0.f};
                    }
            }
        }
    }
}

// ---------------- BatchNorm finish: partials -> affine tables -------------
__global__ void bn_finish2(const float* __restrict__ part, float* __restrict__ stats,
                           const bf16* __restrict__ sc, const bf16* __restrict__ bi) {
    int e = blockIdx.x;   // 256
    int t = threadIdx.x;
    float s = part[(size_t)t * 256 + e] + part[(size_t)(t + 256) * 256 + e];
    float s2 = part[131072 + (size_t)t * 256 + e] + part[131072 + (size_t)(t + 256) * 256 + e];
    __shared__ float rs[256], rs2[256];
    rs[t] = s; rs2[t] = s2;
    __syncthreads();
    for (int k = 128; k > 0; k >>= 1) {
        if (t < k) { rs[t] += rs[t + k]; rs2[t] += rs2[t + k]; }
        __syncthreads();
    }
    if (t == 0) {
        float mu = rs[0] * (1.f / 65536.f);
        float var = rs2[0] * (1.f / 65536.f) - mu * mu;
        float a = rsqrtf(var + 1e-5f) * b2f(sc[e]);
        stats[e] = a;
        stats[256 + e] = b2f(bi[e]) - mu * a;
    }
}

// wb[n,e] = B_?[h,e]*gamma[h]*a[e] with INTERLEAVED rows (n=2h -> re, 2h+1 -> im)
// + fused Bu bias: bubias[n] = gamma[h] * sum_e c[e]*B_?[h,e]
__global__ void pack_wb(const void* __restrict__ B_re, const void* __restrict__ B_im,
                        size_t off, const float* __restrict__ gam,
                        const float* __restrict__ stats,
                        bf16* __restrict__ out, float* __restrict__ bias_out,
                        const int* __restrict__ flag) {
    int f = *flag;
    int n = blockIdx.x;   // 512
    int e = threadIdx.x;
    int h = n >> 1;
    const void* src = (n & 1) ? B_im : B_re;
    float v = ldf(src, off + (size_t)h * 256 + e, f);
    out[(size_t)n * 256 + e] = f2b(v * gam[h] * stats[e]);
    __shared__ float rs[256];
    rs[e] = v * stats[256 + e];
    __syncthreads();
    for (int k = 128; k > 0; k >>= 1) {
        if (e < k) rs[e] += rs[e + k];
        __syncthreads();
    }
    if (e == 0) bias_out[n] = rs[0] * gam[h];
}

// all-layer weight packing up front: 6 layers x (wc 512 + w1t 1024 + w2t 512)
__global__ void pack_all(const void* __restrict__ C_re, const void* __restrict__ C_im,
                         const void* __restrict__ W1, const void* __restrict__ W2,
                         bf16* __restrict__ wc6, bf16* __restrict__ w1t6, bf16* __restrict__ w2t6,
                         const int* __restrict__ flag) {
    int f = *flag;
    int L = blockIdx.x >> 11;          // /2048
    int blk = blockIdx.x & 2047;
    size_t offC = (size_t)L * 65536, offW1 = (size_t)L * 262144, offW2 = (size_t)L * 131072;
    if (blk < 512) {
        // wc rows (k interleaved): k=2h -> C_re[e,h], k=2h+1 -> -C_im[e,h]
        int g = blk * 256 + threadIdx.x;
        int e = g >> 9, k = g & 511, h = k >> 1;
        float v = ldf((k & 1) ? C_im : C_re, offC + (size_t)e * 256 + h, f);
        wc6[(size_t)L * 131072 + g] = f2b((k & 1) ? -v : v);
    } else if (blk < 1536) {
        int g = (blk - 512) * 256 + threadIdx.x;
        int n = g >> 8, k = g & 255;
        w1t6[(size_t)L * 262144 + g] = f2b(ldf(W1, offW1 + (size_t)k * 1024 + n, f));
    } else {
        int g = (blk - 1536) * 256 + threadIdx.x;
        int n = g >> 9, k = g & 511;
        w2t6[(size_t)L * 131072 + g] = f2b(ldf(W2, offW2 + (size_t)k * 256 + n, f));
    }
}

// ---------------- LRU final: fused chunk-prefix + in-place scan ----------
// carry produced by the Bu GEMM epilogue (EPI 6). Each thread first builds
// its chunk's prefix (er = lam^64 * er + carry[c'], c' < c — wave-uniform
// trip count; carry is 2MB L2-resident, 16B/iter), then scans its 64 rows.
__global__ void lru_final(bf16* __restrict__ bu, const float* __restrict__ carry,
                          const float* __restrict__ lam) {
    int gg = blockIdx.x * 256 + threadIdx.x;  // 131072
    int hp = gg & 127, c = (gg >> 7) & 31, b = gg >> 12;
    f4v lm = *(const f4v*)&lam[hp * 4];
    // lam^64 for both h of the pair (6 squarings)
    float q0r = lm[0], q0i = lm[1], q1r = lm[2], q1i = lm[3];
#pragma unroll
    for (int k = 0; k < 6; k++) {
        float n0 = q0r * q0r - q0i * q0i; q0i = 2.f * q0r * q0i; q0r = n0;
        float n1 = q1r * q1r - q1i * q1i; q1i = 2.f * q1r * q1i; q1r = n1;
    }
    float sr0 = 0.f, si0 = 0.f, sr1 = 0.f, si1 = 0.f;
    const f4v* cp = (const f4v*)(carry + ((size_t)b * 32) * 512) + hp;
    for (int cc = 0; cc < c; cc++) {
        f4v cv = *cp;
        float n0 = q0r * sr0 - q0i * si0 + cv[0];
        si0 = q0r * si0 + q0i * sr0 + cv[1]; sr0 = n0;
        float n1 = q1r * sr1 - q1i * si1 + cv[2];
        si1 = q1r * si1 + q1i * sr1 + cv[3]; sr1 = n1;
        cp += 128;   // next chunk (512 floats)
    }
    char* p = (char*)(bu + ((size_t)(b * TLEN + c * TCH)) * 512) + hp * 8;
    for (int t = 0; t < TCH; t++) {
        unsigned long long u = *(const unsigned long long*)p;
        float ur0 = bits2f((unsigned short)u), ui0 = bits2f((unsigned short)(u >> 16));
        float ur1 = bits2f((unsigned short)(u >> 32)), ui1 = bits2f((unsigned short)(u >> 48));
        float nr0 = lm[0] * sr0 - lm[1] * si0 + ur0;
        si0 = lm[0] * si0 + lm[1] * sr0 + ui0; sr0 = nr0;
        float nr1 = lm[2] * sr1 - lm[3] * si1 + ur1;
        si1 = lm[2] * si1 + lm[3] * sr1 + ui1; sr1 = nr1;
        unsigned long long w = (unsigned long long)f2bits(sr0)
                             | ((unsigned long long)f2bits(si0) << 16)
                             | ((unsigned long long)f2bits(sr1) << 32)
                             | ((unsigned long long)f2bits(si1) << 48);
        *(unsigned long long*)p = w;
        p += 1024;
    }
}

// ---------------- head (pool partials come from the last W2's BN-stats) ---
__global__ void head_k(const float* __restrict__ part, const bf16* __restrict__ W_out,
                       const bf16* __restrict__ b_out, void* __restrict__ out,
                       const int* __restrict__ flag) {
    int b = blockIdx.x;
    int tid = threadIdx.x;
    __shared__ float sp[256];
    __shared__ float red[160];
    float s = 0.f;
    for (int c = 0; c < 16; c++) s += part[((size_t)(b * 16 + c)) * 256 + tid];
    sp[tid] = s * (1.f / 2048.f);
    __syncthreads();
    if (tid < 160) {
        int o = tid >> 4, sg = tid & 15;
        float a = 0.f;
        for (int e = sg; e < 256; e += 16) a += sp[e] * b2f(W_out[e * 10 + o]);
        red[tid] = a;
    }
    __syncthreads();
    if (tid < 10) {
        float acc = b2f(b_out[tid]);
        for (int sg = 0; sg < 16; sg++) acc += red[tid * 16 + sg];
        if (*flag) ((float*)out)[b * 10 + tid] = acc;
        else       ((bf16*)out)[b * 10 + tid] = f2b(acc);
    }
}

__global__ void pack_wt_enc(const void* __restrict__ W_enc, bf16* __restrict__ out,
                            const int* __restrict__ flag) {
    int f = *flag;
    int g = blockIdx.x * 256 + threadIdx.x;  // 16384
    int n = g >> 6, k = g & 63;
    out[g] = f2b(ldf(W_enc, (size_t)k * 256 + n, f));
}

extern "C" void kernel_launch(void* const* d_in, const int* in_sizes, int n_in,
                              void* d_out, int out_size, void* d_ws, size_t ws_size,
                              hipStream_t stream) {
    (void)in_sizes; (void)n_in; (void)out_size; (void)ws_size;
    const void* x      = d_in[0];
    const void* W_enc  = d_in[1];
    const void* b_enc  = d_in[2];
    const void* nu_log = d_in[3];
    const void* th_log = d_in[4];
    const void* B_re   = d_in[5];
    const void* B_im   = d_in[6];
    const void* C_re   = d_in[7];
    const void* C_im   = d_in[8];
    const void* Dp     = d_in[9];
    const void* W1     = d_in[10];
    const void* b1     = d_in[11];
    const void* W2     = d_in[12];
    const void* b2     = d_in[13];
    const void* bn_s   = d_in[14];
    const void* bn_b   = d_in[15];
    const void* W_out  = d_in[16];
    const void* b_out  = d_in[17];

    // workspace layout (~178 MB)
    char* w = (char*)d_ws;
    bf16* xc  = (bf16*)w; w += (size_t)MTOT * 256 * 2;   // residual stream
    bf16* y   = (bf16*)w; w += (size_t)MTOT * 256 * 2;   // residual anchor
    bf16* hbn = (bf16*)w; w += (size_t)MTOT * 256 * 2;   // LRU out
    bf16* bu  = (bf16*)w; w += (size_t)MTOT * 512 * 2;   // Bu/hs (interleaved), GLU out
    float* stats  = (float*)w; w += 4096;                // a[256], c[256]
    float* bnpart = (float*)w; w += 1048576;             // stats partials (also pool partials)
    float* carry  = (float*)w; w += 2097152;             // 1024 chunks x 256 h x 2 fp32
    float* lamb   = (float*)w; w += 12288;               // 1536*2 fp32
    float* gamt   = (float*)w; w += 6144;                // 1536 fp32
    float* bubias = (float*)w; w += 2048;                // 512 fp32
    int*   flag   = (int*)w;  w += 256;
    bf16* wt_enc = (bf16*)w; w += 32768;
    bf16* wb   = (bf16*)w; w += 262144;
    bf16* wc6  = (bf16*)w; w += 6 * 262144;              // 1.57 MB
    bf16* w1t6 = (bf16*)w; w += 6 * 524288;              // 3.15 MB
    bf16* w2t6 = (bf16*)w; w += 6 * 262144;              // 1.57 MB
    bf16* b_encb = (bf16*)w; w += 512;
    bf16* Db     = (bf16*)w; w += 3072;
    bf16* b1b    = (bf16*)w; w += 12288;
    bf16* b2b    = (bf16*)w; w += 3072;
    bf16* bnsb   = (bf16*)w; w += 3072;
    bf16* bnbb   = (bf16*)w; w += 3072;
    bf16* Woutb  = (bf16*)w; w += 5120;
    bf16* boutb  = (bf16*)w; w += 32;
    bf16* xb = bu;  // x's bf16 copy aliases bu (dead until first Bu GEMM)

    dim3 blk(256);
    detect_k<<<1, blk, 0, stream>>>((const unsigned short*)x, flag);
    cvt_k4<<<4096, blk, 0, stream>>>(x, xb, 4194304, flag);
    cvt_small<<<60, blk, 0, stream>>>(b_enc, Dp, b1, b2, bn_s, bn_b, W_out, b_out,
                                      b_encb, Db, b1b, b2b, bnsb, bnbb, Woutb, boutb, flag);
    lamgam_k<<<6, blk, 0, stream>>>(nu_log, th_log, lamb, gamt, flag);
    pack_wt_enc<<<64, blk, 0, stream>>>(W_enc, wt_enc, flag);
    pack_all<<<12288, blk, 0, stream>>>(C_re, C_im, W1, W2, wc6, w1t6, w2t6, flag);

    // encoder: [M,64] @ W_enc^T + b_enc -> xc and y (+ BN stats partials)
    gemm_v7<64, 4, 1><<<2048, blk, 0, stream>>>(xb, wt_enc, xc, y, 256,
                                                b_encb, nullptr, nullptr, nullptr, bnpart,
                                                nullptr, nullptr);
    for (int i = 0; i < 6; ++i) {
        bn_finish2<<<256, blk, 0, stream>>>(bnpart, stats, bnsb + i * 256, bnbb + i * 256);
        pack_wb<<<512, blk, 0, stream>>>(B_re, B_im, (size_t)i * 65536, gamt + i * 256,
                                         stats, wb, bubias, flag);
        // Bu = BN(xc) @ (gamma*[B;B])^T -> bu [M,512] + fused chunk-carry
        gemm_v7<256, 8, 6><<<4096, blk, 0, stream>>>(xc, wb, bu, nullptr, 512,
                                                     nullptr, nullptr, nullptr, bubias, nullptr,
                                                     lamb + i * 512, carry);
        // scan (prefix fused): bu <- hs in place
        lru_final<<<512, blk, 0, stream>>>(bu, carry, lamb + i * 512);
        // lru_out = hs @ [C_re;-C_im]^T + D*(a*xc+c) -> hbn [M,256]
        gemm_v7<512, 4, 2><<<2048, blk, 0, stream>>>(bu, wc6 + (size_t)i * 131072, hbn, nullptr, 256,
                                                     nullptr, Db + i * 256, xc, stats, nullptr,
                                                     nullptr, nullptr);
        // fused GLU MLP: bu = (hbn@W1v+b1v)*sigmoid(hbn@W1g+b1g)  [M,512]
        glu_v8<<<2048, blk, 0, stream>>>(hbn, w1t6 + (size_t)i * 262144, bu, b1b + i * 1024);
        // xc = glu @ W2^T + b2 + y (+ BN stats / pool partials for next stage)
        gemm_v7<512, 4, 5><<<2048, blk, 0, stream>>>(bu, w2t6 + (size_t)i * 131072, xc, nullptr, 256,
                                                     b2b + i * 256, nullptr, y, nullptr, bnpart,
                                                     nullptr, nullptr);
    }
    head_k<<<32, blk, 0, stream>>>(bnpart, Woutb, boutb, d_out, flag);
}

// Round 13
// 1370.151 us; speedup vs baseline: 1.0487x; 1.0146x over previous
//
#include <hip/hip_runtime.h>
#include <hip/hip_bf16.h>
#include <math.h>

using bf16 = __hip_bfloat16;
typedef __attribute__((ext_vector_type(8))) short s8v;
typedef __attribute__((ext_vector_type(4))) float f4v;

#define MTOT 65536   // B*T
#define TLEN 2048
#define NCHUNK 32
#define TCH 64

__device__ __forceinline__ float b2f(bf16 x) { return __bfloat162float(x); }
__device__ __forceinline__ bf16 f2b(float x) { return __float2bfloat16(x); }
__device__ __forceinline__ float bits2f(unsigned short u) {
    unsigned int x = ((unsigned int)u) << 16; float f; __builtin_memcpy(&f, &x, 4); return f;
}
__device__ __forceinline__ unsigned short f2bits(float x) {
    bf16 h = f2b(x); unsigned short u; __builtin_memcpy(&u, &h, 2); return u;
}

// flagged load: f32 buffer if f!=0 else bf16 buffer
__device__ __forceinline__ float ldf(const void* p, size_t i, int f) {
    return f ? ((const float*)p)[i] : b2f(((const bf16*)p)[i]);
}

__device__ __forceinline__ void ld_g2l(const void* g, void* l) {
    __builtin_amdgcn_global_load_lds(
        (const __attribute__((address_space(1))) void*)g,
        (__attribute__((address_space(3))) void*)l,
        16, 0, 0);
}

// ---------------- dtype detection ----------------
__global__ void detect_k(const unsigned short* __restrict__ x, int* __restrict__ flag) {
    int tid = threadIdx.x;
    int cnt = 0;
    for (int i = tid; i < 8192; i += 256) {
        int e = (x[i] >> 7) & 0xFF;
        if (e == 0 || e == 0xFF) cnt++;
    }
    __shared__ int red[256];
    red[tid] = cnt;
    __syncthreads();
    for (int s = 128; s > 0; s >>= 1) {
        if (tid < s) red[tid] += red[tid + s];
        __syncthreads();
    }
    if (tid == 0) flag[0] = (red[0] >= 2) ? 1 : 0;
}

// x4-vectorized convert (vector loads: uint2 for bf16 src, float4 for f32 src)
__global__ void cvt_k4(const void* __restrict__ src, bf16* __restrict__ dst, int n,
                       const int* __restrict__ flag) {
    int f = *flag;
    int i = (blockIdx.x * 256 + threadIdx.x) * 4;
    if (i + 3 < n) {
        if (f) {
            float4 v = *(const float4*)((const float*)src + i);
            dst[i] = f2b(v.x); dst[i + 1] = f2b(v.y);
            dst[i + 2] = f2b(v.z); dst[i + 3] = f2b(v.w);
        } else {
            uint2 v = *(const uint2*)((const unsigned short*)src + i);
            unsigned long long u = (unsigned long long)v.x | ((unsigned long long)v.y << 32);
            *(unsigned long long*)(dst + i) = u;   // already bf16 bits, pass through
        }
    } else {
        for (int k = 0; k < 4 && i + k < n; k++) dst[i + k] = f2b(ldf(src, i + k, f));
    }
}

// merged small-tensor converts (60 blocks)
__global__ void cvt_small(const void* b_enc, const void* Dp, const void* b1, const void* b2,
                          const void* bn_s, const void* bn_b, const void* W_out, const void* b_out,
                          bf16* b_encb, bf16* Db, bf16* b1b, bf16* b2b, bf16* bnsb, bf16* bnbb,
                          bf16* Woutb, bf16* boutb, const int* __restrict__ flag) {
    int f = *flag;
    int blk = blockIdx.x, t = threadIdx.x;
    const void* src; bf16* dst; int base, n;
    if (blk < 1)       { src = b_enc; dst = b_encb; base = blk;      n = 256; }
    else if (blk < 7)  { src = Dp;    dst = Db;     base = blk - 1;  n = 1536; }
    else if (blk < 31) { src = b1;    dst = b1b;    base = blk - 7;  n = 6144; }
    else if (blk < 37) { src = b2;    dst = b2b;    base = blk - 31; n = 1536; }
    else if (blk < 43) { src = bn_s;  dst = bnsb;   base = blk - 37; n = 1536; }
    else if (blk < 49) { src = bn_b;  dst = bnbb;   base = blk - 43; n = 1536; }
    else if (blk < 59) { src = W_out; dst = Woutb;  base = blk - 49; n = 2560; }
    else               { src = b_out; dst = boutb;  base = 0;        n = 10; }
    int i = base * 256 + t;
    if (i < n) dst[i] = f2b(ldf(src, i, f));
}

__global__ void lamgam_k(const void* __restrict__ nu, const void* __restrict__ th,
                         float* __restrict__ lamb, float* __restrict__ gamt,
                         const int* __restrict__ flag) {
    int f = *flag;
    int g = blockIdx.x * 256 + threadIdx.x;  // 1536
    float nl = ldf(nu, g, f), tl = ldf(th, g, f);
    float mag = expf(-expf(nl));
    float ang = expf(tl);
    lamb[g * 2] = mag * cosf(ang);
    lamb[g * 2 + 1] = mag * sinf(ang);
    gamt[g] = sqrtf(fmaxf(1.f - mag * mag, 1e-12f));
}

// =====================================================================
// GEMM out[m,n] = sum_k A[m,k]*W[n,k] (+epilogue). 128m x 64n tile,
// 4 waves (each 64x32), BK=32, 3-buffer LDS ring (36KB), depth-2
// prefetch with counted vmcnt(6) (3 reqs/thread/stage), tails 3 -> 0.
// Two barriers per K-step (verified optimum of this family).
// NBN column-siblings of an M-tile land on the same XCD (L2 A reuse).
// EPI 0: +bias -> outB only, + BN-stats partials         (encoder -> y;
//        layer 0 reads y in place of xc, so no duplicate store)
// EPI 2: +Dv[n]*(a[n]*aux+c[n]) -> bf16                  (LRU C-out)
// EPI 5: v+bias+aux[m,n] -> bf16, + BN-stats partials    (W2 + residual;
//        the sum-partial doubles as the pooling partial for the head)
// EPI 6: +fbias[n] (fp32) -> bf16, + FUSED LRU CHUNK CARRY (r9 notes)
// =====================================================================
template<int KK, int NBN, int EPI>
__global__ __launch_bounds__(256)
void gemm_v7(const bf16* __restrict__ A, const bf16* __restrict__ W,
             bf16* __restrict__ outB, bf16* __restrict__ outB2, int ldo,
             const bf16* __restrict__ bias,
             const bf16* __restrict__ Dv, const bf16* __restrict__ aux,
             const float* __restrict__ fstats, float* __restrict__ spart,
             const float* __restrict__ lamp, float* __restrict__ carry)
{
    constexpr int LG = (NBN == 8) ? 3 : 2;
    const int id = blockIdx.x;
    const int xcd = id & 7, q = id >> 3;
    const int bn = q & (NBN - 1);
    const int bm = (q >> LG) * 8 + xcd;

    const int tid = threadIdx.x;
    const int lane = tid & 63, wv = tid >> 6;
    const int wm = wv >> 1, wn = wv & 1;
    const int quad = lane >> 4, cl = lane & 15;

    __shared__ __align__(16) short As[3][128 * 32];
    __shared__ __align__(16) short Ws[3][64 * 32];
    __shared__ float sred[256];

    const char* Ab = (const char*)A + (size_t)bm * 128 * ((size_t)KK * 2);
    const char* Wb = (const char*)W + (size_t)bn * 64 * ((size_t)KK * 2);
    constexpr int ldb = KK * 2;

    auto stage = [&](int t, int bi) {
        const int kb = t * 64;
#pragma unroll
        for (int it = 0; it < 2; ++it) {
            int G = it * 256 + tid;
            int r = G >> 2;
            int gl = (G & 3) ^ ((r >> 1) & 3);
            ld_g2l(Ab + (size_t)r * ldb + kb + gl * 16,
                   (char*)As[bi] + (it * 4 + wv) * 1024);
        }
        {
            int r = tid >> 2;
            int gl = (tid & 3) ^ ((r >> 1) & 3);
            ld_g2l(Wb + (size_t)r * ldb + kb + gl * 16,
                   (char*)Ws[bi] + wv * 1024);
        }
    };

    f4v acc[4][2];
#pragma unroll
    for (int i = 0; i < 4; i++)
#pragma unroll
        for (int j = 0; j < 2; j++) acc[i][j] = (f4v){0.f, 0.f, 0.f, 0.f};

    constexpr int NT = KK >> 5;
    stage(0, 0);
    if (NT > 1) stage(1, 1);
#pragma unroll
    for (int t = 0; t < NT; ++t) {
        if (t + 2 < NT) {
            stage(t + 2, (t + 2) % 3);
            asm volatile("s_waitcnt vmcnt(6)" ::: "memory");
        } else if (t + 1 < NT) {
            asm volatile("s_waitcnt vmcnt(3)" ::: "memory");
        } else {
            asm volatile("s_waitcnt vmcnt(0)" ::: "memory");
        }
        asm volatile("s_barrier" ::: "memory");
        const char* Ac = (const char*)As[t % 3];
        const char* Wc = (const char*)Ws[t % 3];
        s8v af[4], bw[2];
#pragma unroll
        for (int i = 0; i < 4; i++) {
            int r = wm * 64 + i * 16 + cl;
            af[i] = *(const s8v*)(Ac + r * 64 + ((quad ^ ((r >> 1) & 3)) * 16));
        }
#pragma unroll
        for (int j = 0; j < 2; j++) {
            int r = wn * 32 + j * 16 + cl;
            bw[j] = *(const s8v*)(Wc + r * 64 + ((quad ^ ((r >> 1) & 3)) * 16));
        }
#pragma unroll
        for (int i = 0; i < 4; i++)
#pragma unroll
            for (int j = 0; j < 2; j++)
                acc[i][j] = __builtin_amdgcn_mfma_f32_16x16x32_bf16(af[i], bw[j], acc[i][j], 0, 0, 0);
        asm volatile("s_barrier" ::: "memory");
    }

    const size_t ld = (size_t)ldo;
    constexpr bool STATS = (EPI == 0 || EPI == 5);
#pragma unroll
    for (int j = 0; j < 2; j++) {
        float ss = 0.f, ss2 = 0.f;
        const int n = bn * 64 + wn * 32 + j * 16 + cl;
        // ---- carry-weight tables (EPI 6 only) ----
        float Er[4], Ei[4], Cr[4], Cim[4];
        if constexpr (EPI == 6) {
            int h = n >> 1;
            float lr = lamp[h * 2], li = lamp[h * 2 + 1];
            float a2r = lr * lr - li * li, a2i = 2.f * lr * li;          // lam^2
            float a3r = a2r * lr - a2i * li, a3i = a2r * li + a2i * lr;  // lam^3
            float l4r = a2r * a2r - a2i * a2i, l4i = 2.f * a2r * a2i;    // lam^4
            float l8r = l4r * l4r - l4i * l4i, l8i = 2.f * l4r * l4i;
            float l12r = l8r * l4r - l8i * l4i, l12i = l8r * l4i + l8i * l4r;
            float Br = (quad == 0) ? l12r : (quad == 1) ? l8r : (quad == 2) ? l4r : 1.f;
            float Bi = (quad == 0) ? l12i : (quad == 1) ? l8i : (quad == 2) ? l4i : 0.f;
            float Ar[4] = { a3r, a2r, lr, 1.f };
            float Ai[4] = { a3i, a2i, li, 0.f };
#pragma unroll
            for (int r4 = 0; r4 < 4; r4++) {
                Er[r4] = Ar[r4] * Br - Ai[r4] * Bi;
                Ei[r4] = Ar[r4] * Bi + Ai[r4] * Br;
            }
            float l16r = l12r * l4r - l12i * l4i, l16i = l12r * l4i + l12i * l4r;
            float l32r = l16r * l16r - l16i * l16i, l32i = 2.f * l16r * l16i;
            float l48r = l32r * l16r - l32i * l16i, l48i = l32r * l16i + l32i * l16r;
            Cr[0] = l48r; Cim[0] = l48i;   // i=0 -> lam^48
            Cr[1] = l32r; Cim[1] = l32i;
            Cr[2] = l16r; Cim[2] = l16i;
            Cr[3] = 1.f;  Cim[3] = 0.f;
        }
        float Sr = 0.f, Si = 0.f;
#pragma unroll
        for (int i = 0; i < 4; i++) {
#pragma unroll
            for (int r4 = 0; r4 < 4; r4++) {
                int m = bm * 128 + wm * 64 + i * 16 + quad * 4 + r4;
                size_t idx = (size_t)m * ld + n;
                float v = acc[i][j][r4];
                if (EPI == 0) {
                    v += b2f(bias[n]);
                    outB[idx] = f2b(v);
                } else if (EPI == 2) {
                    v += b2f(Dv[n]) * (fstats[n] * b2f(aux[idx]) + fstats[256 + n]);
                    outB[idx] = f2b(v);
                } else if (EPI == 5) {
                    v += b2f(bias[n]) + b2f(aux[idx]);
                    outB[idx] = f2b(v);
                } else if (EPI == 6) {
                    v += fstats[n];
                    bf16 ob = f2b(v);
                    outB[idx] = ob;
                    float vr = b2f(ob);
                    float wr = Er[r4] * Cr[i] - Ei[r4] * Cim[i];
                    float wi = Er[r4] * Cim[i] + Ei[r4] * Cr[i];
                    Sr += vr * wr;
                    Si += vr * wi;
                }
                if (STATS) { ss += v; ss2 += v * v; }
            }
        }
        if constexpr (EPI == 6) {
            Sr += __shfl_xor(Sr, 16); Sr += __shfl_xor(Sr, 32);
            Si += __shfl_xor(Si, 16); Si += __shfl_xor(Si, 32);
            float pSr = __shfl_xor(Sr, 1), pSi = __shfl_xor(Si, 1);
            if (quad == 0 && (cl & 1) == 0) {
                size_t gc = (size_t)(bm * 2 + wm);      // global time-chunk
                size_t ci = (gc * 256 + (size_t)(n >> 1)) * 2;
                carry[ci]     = Sr - pSi;
                carry[ci + 1] = Si + pSr;
            }
        }
        if (STATS) {
            ss += __shfl_xor(ss, 16);  ss += __shfl_xor(ss, 32);
            ss2 += __shfl_xor(ss2, 16); ss2 += __shfl_xor(ss2, 32);
            if (lane < 16) {
                int nl = wn * 32 + j * 16 + lane;
                sred[wm * 64 + nl] = ss;
                sred[128 + wm * 64 + nl] = ss2;
            }
        }
    }
    if constexpr (STATS) {
        __syncthreads();
        if (tid < 64) {
            float sv = sred[tid] + sred[64 + tid];
            float sv2 = sred[128 + tid] + sred[192 + tid];
            spart[(size_t)bm * 256 + bn * 64 + tid] = sv;
            spart[131072 + (size_t)bm * 256 + bn * 64 + tid] = sv2;
        }
    }
}

// ---------------- fused GLU: TWO 128m x (64v+64g) tiles per block --------
// 4 waves each 64m x (32v+32g). 3-buffer ring 48KB; ring runs continuously
// across the tile boundary. Counted waits account for the 32 epilogue
// stores at the tile boundary (G in {8,9}: vmcnt(40)).
__global__ __launch_bounds__(256)
void glu_v8(const bf16* __restrict__ A, const bf16* __restrict__ W,
            bf16* __restrict__ outB, const bf16* __restrict__ bias)
{
    constexpr int KK = 256;
    constexpr int GT = 16;
    const int id = blockIdx.x;
    const int xcd = id & 7, q = id >> 3;
    const int nb = q & 7;
    const int mgrp = (q >> 3) * 8 + xcd;       // 0..255

    const int tid = threadIdx.x;
    const int lane = tid & 63, wv = tid >> 6;
    const int wm = wv >> 1, wn = wv & 1;
    const int quad = lane >> 4, cl = lane & 15;

    __shared__ __align__(16) short As[3][128 * 32];
    __shared__ __align__(16) short Vs[3][64 * 32];
    __shared__ __align__(16) short Gs[3][64 * 32];

    const char* Abase = (const char*)A;
    const char* Vb = (const char*)W + (size_t)(nb * 64) * ((size_t)KK * 2);
    const char* Gb = (const char*)W + (size_t)(512 + nb * 64) * ((size_t)KK * 2);
    constexpr int ldb = KK * 2;

    auto stage = [&](int G) {
        const int tile = G >> 3;
        const int kb = (G & 7) * 64;
        const int bi = G % 3;
        const char* Ab = Abase + (size_t)(mgrp * 2 + tile) * 128 * ((size_t)KK * 2);
#pragma unroll
        for (int it = 0; it < 2; ++it) {
            int Gt = it * 256 + tid;
            int r = Gt >> 2;
            int gl = (Gt & 3) ^ ((r >> 1) & 3);
            ld_g2l(Ab + (size_t)r * ldb + kb + gl * 16,
                   (char*)As[bi] + (it * 4 + wv) * 1024);
        }
        {
            int r = tid >> 2;
            int gl = (tid & 3) ^ ((r >> 1) & 3);
            ld_g2l(Vb + (size_t)r * ldb + kb + gl * 16, (char*)Vs[bi] + wv * 1024);
            ld_g2l(Gb + (size_t)r * ldb + kb + gl * 16, (char*)Gs[bi] + wv * 1024);
        }
    };

    f4v accv[4][2], accg[4][2];
#pragma unroll
    for (int i = 0; i < 4; i++)
#pragma unroll
        for (int j = 0; j < 2; j++) {
            accv[i][j] = (f4v){0.f, 0.f, 0.f, 0.f};
            accg[i][j] = (f4v){0.f, 0.f, 0.f, 0.f};
        }

    stage(0);
    stage(1);
#pragma unroll
    for (int G = 0; G < GT; ++G) {
        if (G + 2 < GT) {
            stage(G + 2);
            if (G == 8 || G == 9) {
                asm volatile("s_waitcnt vmcnt(40)" ::: "memory");
            } else {
                asm volatile("s_waitcnt vmcnt(8)" ::: "memory");
            }
        } else if (G + 1 < GT) {
            asm volatile("s_waitcnt vmcnt(4)" ::: "memory");
        } else {
            asm volatile("s_waitcnt vmcnt(0)" ::: "memory");
        }
        asm volatile("s_barrier" ::: "memory");
        const char* Ac = (const char*)As[G % 3];
        const char* Vc = (const char*)Vs[G % 3];
        const char* Gc = (const char*)Gs[G % 3];
        s8v af[4], bv[2], bg[2];
#pragma unroll
        for (int i = 0; i < 4; i++) {
            int r = wm * 64 + i * 16 + cl;
            af[i] = *(const s8v*)(Ac + r * 64 + ((quad ^ ((r >> 1) & 3)) * 16));
        }
#pragma unroll
        for (int j = 0; j < 2; j++) {
            int r = wn * 32 + j * 16 + cl;
            int off = r * 64 + ((quad ^ ((r >> 1) & 3)) * 16);
            bv[j] = *(const s8v*)(Vc + off);
            bg[j] = *(const s8v*)(Gc + off);
        }
#pragma unroll
        for (int i = 0; i < 4; i++)
#pragma unroll
            for (int j = 0; j < 2; j++) {
                accv[i][j] = __builtin_amdgcn_mfma_f32_16x16x32_bf16(af[i], bv[j], accv[i][j], 0, 0, 0);
                accg[i][j] = __builtin_amdgcn_mfma_f32_16x16x32_bf16(af[i], bg[j], accg[i][j], 0, 0, 0);
            }
        asm volatile("s_barrier" ::: "memory");

        if ((G & 7) == 7) {
            const int bm = mgrp * 2 + (G >> 3);
#pragma unroll
            for (int i = 0; i < 4; i++) {
#pragma unroll
                for (int j = 0; j < 2; j++) {
#pragma unroll
                    for (int r4 = 0; r4 < 4; r4++) {
                        int m = bm * 128 + wm * 64 + i * 16 + quad * 4 + r4;
                        int n = nb * 64 + wn * 32 + j * 16 + cl;
                        float v = accv[i][j][r4] + b2f(bias[n]);
                        float g = accg[i][j][r4] + b2f(bias[512 + n]);
                        outB[(size_t)m * 512 + n] = f2b(v * (1.f / (1.f + __expf(-g))));
                    }
                }
            }
            if (G + 1 < GT) {
#pragma unroll
                for (int i = 0; i < 4; i++)
#pragma unroll
                    for (int j = 0; j < 2; j++) {
                        accv[i][j] = (f4v){0.f, 0.f, 0.f, 0.f};
                        accg[i][j] = (f4v){0.f, 0.f, 0.f, 0.f};
                    }
            }
        }
    }
}

// ---------------- BatchNorm finish: partials -> affine tables -------------
__global__ void bn_finish2(const float* __restrict__ part, float* __restrict__ stats,
                           const bf16* __restrict__ sc, const bf16* __restrict__ bi) {
    int e = blockIdx.x;   // 256
    int t = threadIdx.x;
    float s = part[(size_t)t * 256 + e] + part[(size_t)(t + 256) * 256 + e];
    float s2 = part[131072 + (size_t)t * 256 + e] + part[131072 + (size_t)(t + 256) * 256 + e];
    __shared__ float rs[256], rs2[256];
    rs[t] = s; rs2[t] = s2;
    __syncthreads();
    for (int k = 128; k > 0; k >>= 1) {
        if (t < k) { rs[t] += rs[t + k]; rs2[t] += rs2[t + k]; }
        __syncthreads();
    }
    if (t == 0) {
        float mu = rs[0] * (1.f / 65536.f);
        float var = rs2[0] * (1.f / 65536.f) - mu * mu;
        float a = rsqrtf(var + 1e-5f) * b2f(sc[e]);
        stats[e] = a;
        stats[256 + e] = b2f(bi[e]) - mu * a;
    }
}

// wb[n,e] = B_?[h,e]*gamma[h]*a[e] with INTERLEAVED rows (n=2h -> re, 2h+1 -> im)
// + fused Bu bias: bubias[n] = gamma[h] * sum_e c[e]*B_?[h,e]
__global__ void pack_wb(const void* __restrict__ B_re, const void* __restrict__ B_im,
                        size_t off, const float* __restrict__ gam,
                        const float* __restrict__ stats,
                        bf16* __restrict__ out, float* __restrict__ bias_out,
                        const int* __restrict__ flag) {
    int f = *flag;
    int n = blockIdx.x;   // 512
    int e = threadIdx.x;
    int h = n >> 1;
    const void* src = (n & 1) ? B_im : B_re;
    float v = ldf(src, off + (size_t)h * 256 + e, f);
    out[(size_t)n * 256 + e] = f2b(v * gam[h] * stats[e]);
    __shared__ float rs[256];
    rs[e] = v * stats[256 + e];
    __syncthreads();
    for (int k = 128; k > 0; k >>= 1) {
        if (e < k) rs[e] += rs[e + k];
        __syncthreads();
    }
    if (e == 0) bias_out[n] = rs[0] * gam[h];
}

// all-layer weight packing up front: 6 layers x (wc 512 + w1t 1024 + w2t 512)
__global__ void pack_all(const void* __restrict__ C_re, const void* __restrict__ C_im,
                         const void* __restrict__ W1, const void* __restrict__ W2,
                         bf16* __restrict__ wc6, bf16* __restrict__ w1t6, bf16* __restrict__ w2t6,
                         const int* __restrict__ flag) {
    int f = *flag;
    int L = blockIdx.x >> 11;          // /2048
    int blk = blockIdx.x & 2047;
    size_t offC = (size_t)L * 65536, offW1 = (size_t)L * 262144, offW2 = (size_t)L * 131072;
    if (blk < 512) {
        // wc rows (k interleaved): k=2h -> C_re[e,h], k=2h+1 -> -C_im[e,h]
        int g = blk * 256 + threadIdx.x;
        int e = g >> 9, k = g & 511, h = k >> 1;
        float v = ldf((k & 1) ? C_im : C_re, offC + (size_t)e * 256 + h, f);
        wc6[(size_t)L * 131072 + g] = f2b((k & 1) ? -v : v);
    } else if (blk < 1536) {
        int g = (blk - 512) * 256 + threadIdx.x;
        int n = g >> 8, k = g & 255;
        w1t6[(size_t)L * 262144 + g] = f2b(ldf(W1, offW1 + (size_t)k * 1024 + n, f));
    } else {
        int g = (blk - 1536) * 256 + threadIdx.x;
        int n = g >> 9, k = g & 511;
        w2t6[(size_t)L * 131072 + g] = f2b(ldf(W2, offW2 + (size_t)k * 256 + n, f));
    }
}

// ---------------- LRU final: fused chunk-prefix + in-place scan ----------
__global__ void lru_final(bf16* __restrict__ bu, const float* __restrict__ carry,
                          const float* __restrict__ lam) {
    int gg = blockIdx.x * 256 + threadIdx.x;  // 131072
    int hp = gg & 127, c = (gg >> 7) & 31, b = gg >> 12;
    f4v lm = *(const f4v*)&lam[hp * 4];
    // lam^64 for both h of the pair (6 squarings)
    float q0r = lm[0], q0i = lm[1], q1r = lm[2], q1i = lm[3];
#pragma unroll
    for (int k = 0; k < 6; k++) {
        float n0 = q0r * q0r - q0i * q0i; q0i = 2.f * q0r * q0i; q0r = n0;
        float n1 = q1r * q1r - q1i * q1i; q1i = 2.f * q1r * q1i; q1r = n1;
    }
    float sr0 = 0.f, si0 = 0.f, sr1 = 0.f, si1 = 0.f;
    const f4v* cp = (const f4v*)(carry + ((size_t)b * 32) * 512) + hp;
    for (int cc = 0; cc < c; cc++) {
        f4v cv = *cp;
        float n0 = q0r * sr0 - q0i * si0 + cv[0];
        si0 = q0r * si0 + q0i * sr0 + cv[1]; sr0 = n0;
        float n1 = q1r * sr1 - q1i * si1 + cv[2];
        si1 = q1r * si1 + q1i * sr1 + cv[3]; sr1 = n1;
        cp += 128;   // next chunk (512 floats)
    }
    char* p = (char*)(bu + ((size_t)(b * TLEN + c * TCH)) * 512) + hp * 8;
    for (int t = 0; t < TCH; t++) {
        unsigned long long u = *(const unsigned long long*)p;
        float ur0 = bits2f((unsigned short)u), ui0 = bits2f((unsigned short)(u >> 16));
        float ur1 = bits2f((unsigned short)(u >> 32)), ui1 = bits2f((unsigned short)(u >> 48));
        float nr0 = lm[0] * sr0 - lm[1] * si0 + ur0;
        si0 = lm[0] * si0 + lm[1] * sr0 + ui0; sr0 = nr0;
        float nr1 = lm[2] * sr1 - lm[3] * si1 + ur1;
        si1 = lm[2] * si1 + lm[3] * sr1 + ui1; sr1 = nr1;
        unsigned long long w = (unsigned long long)f2bits(sr0)
                             | ((unsigned long long)f2bits(si0) << 16)
                             | ((unsigned long long)f2bits(sr1) << 32)
                             | ((unsigned long long)f2bits(si1) << 48);
        *(unsigned long long*)p = w;
        p += 1024;
    }
}

// ---------------- head (pool partials come from the last W2's BN-stats) ---
__global__ void head_k(const float* __restrict__ part, const bf16* __restrict__ W_out,
                       const bf16* __restrict__ b_out, void* __restrict__ out,
                       const int* __restrict__ flag) {
    int b = blockIdx.x;
    int tid = threadIdx.x;
    __shared__ float sp[256];
    __shared__ float red[160];
    float s = 0.f;
    for (int c = 0; c < 16; c++) s += part[((size_t)(b * 16 + c)) * 256 + tid];
    sp[tid] = s * (1.f / 2048.f);
    __syncthreads();
    if (tid < 160) {
        int o = tid >> 4, sg = tid & 15;
        float a = 0.f;
        for (int e = sg; e < 256; e += 16) a += sp[e] * b2f(W_out[e * 10 + o]);
        red[tid] = a;
    }
    __syncthreads();
    if (tid < 10) {
        float acc = b2f(b_out[tid]);
        for (int sg = 0; sg < 16; sg++) acc += red[tid * 16 + sg];
        if (*flag) ((float*)out)[b * 10 + tid] = acc;
        else       ((bf16*)out)[b * 10 + tid] = f2b(acc);
    }
}

__global__ void pack_wt_enc(const void* __restrict__ W_enc, bf16* __restrict__ out,
                            const int* __restrict__ flag) {
    int f = *flag;
    int g = blockIdx.x * 256 + threadIdx.x;  // 16384
    int n = g >> 6, k = g & 63;
    out[g] = f2b(ldf(W_enc, (size_t)k * 256 + n, f));
}

extern "C" void kernel_launch(void* const* d_in, const int* in_sizes, int n_in,
                              void* d_out, int out_size, void* d_ws, size_t ws_size,
                              hipStream_t stream) {
    (void)in_sizes; (void)n_in; (void)out_size; (void)ws_size;
    const void* x      = d_in[0];
    const void* W_enc  = d_in[1];
    const void* b_enc  = d_in[2];
    const void* nu_log = d_in[3];
    const void* th_log = d_in[4];
    const void* B_re   = d_in[5];
    const void* B_im   = d_in[6];
    const void* C_re   = d_in[7];
    const void* C_im   = d_in[8];
    const void* Dp     = d_in[9];
    const void* W1     = d_in[10];
    const void* b1     = d_in[11];
    const void* W2     = d_in[12];
    const void* b2     = d_in[13];
    const void* bn_s   = d_in[14];
    const void* bn_b   = d_in[15];
    const void* W_out  = d_in[16];
    const void* b_out  = d_in[17];

    // workspace layout (~178 MB)
    char* w = (char*)d_ws;
    bf16* xc  = (bf16*)w; w += (size_t)MTOT * 256 * 2;   // residual stream
    bf16* y   = (bf16*)w; w += (size_t)MTOT * 256 * 2;   // residual anchor (= encoder out)
    bf16* hbn = (bf16*)w; w += (size_t)MTOT * 256 * 2;   // LRU out
    bf16* bu  = (bf16*)w; w += (size_t)MTOT * 512 * 2;   // Bu/hs (interleaved), GLU out
    float* stats  = (float*)w; w += 4096;                // a[256], c[256]
    float* bnpart = (float*)w; w += 1048576;             // stats partials (also pool partials)
    float* carry  = (float*)w; w += 2097152;             // 1024 chunks x 256 h x 2 fp32
    float* lamb   = (float*)w; w += 12288;               // 1536*2 fp32
    float* gamt   = (float*)w; w += 6144;                // 1536 fp32
    float* bubias = (float*)w; w += 2048;                // 512 fp32
    int*   flag   = (int*)w;  w += 256;
    bf16* wt_enc = (bf16*)w; w += 32768;
    bf16* wb   = (bf16*)w; w += 262144;
    bf16* wc6  = (bf16*)w; w += 6 * 262144;              // 1.57 MB
    bf16* w1t6 = (bf16*)w; w += 6 * 524288;              // 3.15 MB
    bf16* w2t6 = (bf16*)w; w += 6 * 262144;              // 1.57 MB
    bf16* b_encb = (bf16*)w; w += 512;
    bf16* Db     = (bf16*)w; w += 3072;
    bf16* b1b    = (bf16*)w; w += 12288;
    bf16* b2b    = (bf16*)w; w += 3072;
    bf16* bnsb   = (bf16*)w; w += 3072;
    bf16* bnbb   = (bf16*)w; w += 3072;
    bf16* Woutb  = (bf16*)w; w += 5120;
    bf16* boutb  = (bf16*)w; w += 32;
    bf16* xb = bu;  // x's bf16 copy aliases bu (dead until first Bu GEMM)

    dim3 blk(256);
    detect_k<<<1, blk, 0, stream>>>((const unsigned short*)x, flag);
    cvt_k4<<<4096, blk, 0, stream>>>(x, xb, 4194304, flag);
    cvt_small<<<60, blk, 0, stream>>>(b_enc, Dp, b1, b2, bn_s, bn_b, W_out, b_out,
                                      b_encb, Db, b1b, b2b, bnsb, bnbb, Woutb, boutb, flag);
    lamgam_k<<<6, blk, 0, stream>>>(nu_log, th_log, lamb, gamt, flag);
    pack_wt_enc<<<64, blk, 0, stream>>>(W_enc, wt_enc, flag);
    pack_all<<<12288, blk, 0, stream>>>(C_re, C_im, W1, W2, wc6, w1t6, w2t6, flag);

    // encoder: [M,64] @ W_enc^T + b_enc -> y only (+ BN stats partials);
    // layer 0 reads y wherever xc would be read (xc first written by layer-0 W2)
    gemm_v7<64, 4, 0><<<2048, blk, 0, stream>>>(xb, wt_enc, y, nullptr, 256,
                                                b_encb, nullptr, nullptr, nullptr, bnpart,
                                                nullptr, nullptr);
    for (int i = 0; i < 6; ++i) {
        const bf16* xin = (i == 0) ? y : xc;   // residual-stream source for this layer
        bn_finish2<<<256, blk, 0, stream>>>(bnpart, stats, bnsb + i * 256, bnbb + i * 256);
        pack_wb<<<512, blk, 0, stream>>>(B_re, B_im, (size_t)i * 65536, gamt + i * 256,
                                         stats, wb, bubias, flag);
        // Bu = BN(xin) @ (gamma*[B;B])^T -> bu [M,512] + fused chunk-carry
        gemm_v7<256, 8, 6><<<4096, blk, 0, stream>>>(xin, wb, bu, nullptr, 512,
                                                     nullptr, nullptr, nullptr, bubias, nullptr,
                                                     lamb + i * 512, carry);
        // scan (prefix fused): bu <- hs in place
        lru_final<<<512, blk, 0, stream>>>(bu, carry, lamb + i * 512);
        // lru_out = hs @ [C_re;-C_im]^T + D*(a*xin+c) -> hbn [M,256]
        gemm_v7<512, 4, 2><<<2048, blk, 0, stream>>>(bu, wc6 + (size_t)i * 131072, hbn, nullptr, 256,
                                                     nullptr, Db + i * 256, xin, stats, nullptr,
                                                     nullptr, nullptr);
        // fused GLU MLP: bu = (hbn@W1v+b1v)*sigmoid(hbn@W1g+b1g)  [M,512]
        glu_v8<<<2048, blk, 0, stream>>>(hbn, w1t6 + (size_t)i * 262144, bu, b1b + i * 1024);
        // xc = glu @ W2^T + b2 + y (+ BN stats / pool partials for next stage)
        gemm_v7<512, 4, 5><<<2048, blk, 0, stream>>>(bu, w2t6 + (size_t)i * 131072, xc, nullptr, 256,
                                                     b2b + i * 256, nullptr, y, nullptr, bnpart,
                                                     nullptr, nullptr);
    }
    head_k<<<32, blk, 0, stream>>>(bnpart, Woutb, boutb, d_out, flag);
}

// Round 14
// 1357.661 us; speedup vs baseline: 1.0584x; 1.0092x over previous
//
#include <hip/hip_runtime.h>
#include <hip/hip_bf16.h>
#include <math.h>

using bf16 = __hip_bfloat16;
typedef __attribute__((ext_vector_type(8))) short s8v;
typedef __attribute__((ext_vector_type(4))) float f4v;

#define MTOT 65536   // B*T
#define TLEN 2048
#define NCHUNK 32
#define TCH 64

__device__ __forceinline__ float b2f(bf16 x) { return __bfloat162float(x); }
__device__ __forceinline__ bf16 f2b(float x) { return __float2bfloat16(x); }
__device__ __forceinline__ float bits2f(unsigned short u) {
    unsigned int x = ((unsigned int)u) << 16; float f; __builtin_memcpy(&f, &x, 4); return f;
}
__device__ __forceinline__ unsigned short f2bits(float x) {
    bf16 h = f2b(x); unsigned short u; __builtin_memcpy(&u, &h, 2); return u;
}

// flagged load: f32 buffer if f!=0 else bf16 buffer
__device__ __forceinline__ float ldf(const void* p, size_t i, int f) {
    return f ? ((const float*)p)[i] : b2f(((const bf16*)p)[i]);
}

__device__ __forceinline__ void ld_g2l(const void* g, void* l) {
    __builtin_amdgcn_global_load_lds(
        (const __attribute__((address_space(1))) void*)g,
        (__attribute__((address_space(3))) void*)l,
        16, 0, 0);
}

// ---------------- dtype detection ----------------
__global__ void detect_k(const unsigned short* __restrict__ x, int* __restrict__ flag) {
    int tid = threadIdx.x;
    int cnt = 0;
    for (int i = tid; i < 8192; i += 256) {
        int e = (x[i] >> 7) & 0xFF;
        if (e == 0 || e == 0xFF) cnt++;
    }
    __shared__ int red[256];
    red[tid] = cnt;
    __syncthreads();
    for (int s = 128; s > 0; s >>= 1) {
        if (tid < s) red[tid] += red[tid + s];
        __syncthreads();
    }
    if (tid == 0) flag[0] = (red[0] >= 2) ? 1 : 0;
}

// convert only needed when input is f32 (flag=1); bf16 input is consumed
// in place by the encoder (identical layout), so skip the copy entirely.
__global__ void cvt_k4(const void* __restrict__ src, bf16* __restrict__ dst, int n,
                       const int* __restrict__ flag) {
    if (*flag == 0) return;
    int i = (blockIdx.x * 256 + threadIdx.x) * 4;
    if (i + 3 < n) {
        float4 v = *(const float4*)((const float*)src + i);
        dst[i] = f2b(v.x); dst[i + 1] = f2b(v.y);
        dst[i + 2] = f2b(v.z); dst[i + 3] = f2b(v.w);
    } else {
        for (int k = 0; k < 4 && i + k < n; k++) dst[i + k] = f2b(((const float*)src)[i + k]);
    }
}

// merged setup: small-tensor converts (60 blk) + lambda/gamma (6) + enc-weight pack (64)
__global__ void setup_all(const void* b_enc, const void* Dp, const void* b1, const void* b2,
                          const void* bn_s, const void* bn_b, const void* W_out, const void* b_out,
                          const void* nu, const void* th, const void* W_enc,
                          bf16* b_encb, bf16* Db, bf16* b1b, bf16* b2b, bf16* bnsb, bf16* bnbb,
                          bf16* Woutb, bf16* boutb,
                          float* lamb, float* gamt, bf16* wt_enc,
                          const int* __restrict__ flag) {
    int f = *flag;
    int blk = blockIdx.x, t = threadIdx.x;
    if (blk < 60) {
        const void* src; bf16* dst; int base, n;
        if (blk < 1)       { src = b_enc; dst = b_encb; base = blk;      n = 256; }
        else if (blk < 7)  { src = Dp;    dst = Db;     base = blk - 1;  n = 1536; }
        else if (blk < 31) { src = b1;    dst = b1b;    base = blk - 7;  n = 6144; }
        else if (blk < 37) { src = b2;    dst = b2b;    base = blk - 31; n = 1536; }
        else if (blk < 43) { src = bn_s;  dst = bnsb;   base = blk - 37; n = 1536; }
        else if (blk < 49) { src = bn_b;  dst = bnbb;   base = blk - 43; n = 1536; }
        else if (blk < 59) { src = W_out; dst = Woutb;  base = blk - 49; n = 2560; }
        else               { src = b_out; dst = boutb;  base = 0;        n = 10; }
        int i = base * 256 + t;
        if (i < n) dst[i] = f2b(ldf(src, i, f));
    } else if (blk < 66) {
        int g = (blk - 60) * 256 + t;   // 1536
        float nl = ldf(nu, g, f), tl = ldf(th, g, f);
        float mag = expf(-expf(nl));
        float ang = expf(tl);
        lamb[g * 2] = mag * cosf(ang);
        lamb[g * 2 + 1] = mag * sinf(ang);
        gamt[g] = sqrtf(fmaxf(1.f - mag * mag, 1e-12f));
    } else {
        int g = (blk - 66) * 256 + t;   // 16384
        int n = g >> 6, k = g & 63;
        wt_enc[g] = f2b(ldf(W_enc, (size_t)k * 256 + n, f));
    }
}

// =====================================================================
// GEMM out[m,n] = sum_k A[m,k]*W[n,k] (+epilogue). 128m x 64n tile,
// 4 waves (each 64x32), BK=32, 3-buffer LDS ring (36KB), depth-2
// prefetch with counted vmcnt(6) (3 reqs/thread/stage), tails 3 -> 0.
// Two barriers per K-step (verified optimum of this family).
// NBN column-siblings of an M-tile land on the same XCD (L2 A reuse).
// EPI 0: +bias -> outB only, + BN-stats partials; A chosen on DEVICE:
//        flag ? A (cvt'd xb) : Aalt (raw bf16 x) — same layout  (encoder)
// EPI 2: +Dv[n]*(a[n]*aux+c[n]) -> bf16                  (LRU C-out)
// EPI 5: v+bias+aux[m,n] -> bf16, + BN-stats partials    (W2 + residual;
//        the sum-partial doubles as the pooling partial for the head)
// EPI 6: +fbias[n] (fp32) -> bf16, + FUSED LRU CHUNK CARRY (r9 notes)
// =====================================================================
template<int KK, int NBN, int EPI>
__global__ __launch_bounds__(256)
void gemm_v7(const bf16* __restrict__ A, const bf16* __restrict__ W,
             bf16* __restrict__ outB, bf16* __restrict__ outB2, int ldo,
             const bf16* __restrict__ bias,
             const bf16* __restrict__ Dv, const bf16* __restrict__ aux,
             const float* __restrict__ fstats, float* __restrict__ spart,
             const float* __restrict__ lamp, float* __restrict__ carry,
             const bf16* __restrict__ Aalt, const int* __restrict__ flagp)
{
    constexpr int LG = (NBN == 8) ? 3 : 2;
    const int id = blockIdx.x;
    const int xcd = id & 7, q = id >> 3;
    const int bn = q & (NBN - 1);
    const int bm = (q >> LG) * 8 + xcd;

    const int tid = threadIdx.x;
    const int lane = tid & 63, wv = tid >> 6;
    const int wm = wv >> 1, wn = wv & 1;
    const int quad = lane >> 4, cl = lane & 15;

    __shared__ __align__(16) short As[3][128 * 32];
    __shared__ __align__(16) short Ws[3][64 * 32];
    __shared__ float sred[256];

    const bf16* Aeff = A;
    if constexpr (EPI == 0) { if (*flagp == 0) Aeff = Aalt; }
    const char* Ab = (const char*)Aeff + (size_t)bm * 128 * ((size_t)KK * 2);
    const char* Wb = (const char*)W + (size_t)bn * 64 * ((size_t)KK * 2);
    constexpr int ldb = KK * 2;

    auto stage = [&](int t, int bi) {
        const int kb = t * 64;
#pragma unroll
        for (int it = 0; it < 2; ++it) {
            int G = it * 256 + tid;
            int r = G >> 2;
            int gl = (G & 3) ^ ((r >> 1) & 3);
            ld_g2l(Ab + (size_t)r * ldb + kb + gl * 16,
                   (char*)As[bi] + (it * 4 + wv) * 1024);
        }
        {
            int r = tid >> 2;
            int gl = (tid & 3) ^ ((r >> 1) & 3);
            ld_g2l(Wb + (size_t)r * ldb + kb + gl * 16,
                   (char*)Ws[bi] + wv * 1024);
        }
    };

    f4v acc[4][2];
#pragma unroll
    for (int i = 0; i < 4; i++)
#pragma unroll
        for (int j = 0; j < 2; j++) acc[i][j] = (f4v){0.f, 0.f, 0.f, 0.f};

    constexpr int NT = KK >> 5;
    stage(0, 0);
    if (NT > 1) stage(1, 1);
#pragma unroll
    for (int t = 0; t < NT; ++t) {
        if (t + 2 < NT) {
            stage(t + 2, (t + 2) % 3);
            asm volatile("s_waitcnt vmcnt(6)" ::: "memory");
        } else if (t + 1 < NT) {
            asm volatile("s_waitcnt vmcnt(3)" ::: "memory");
        } else {
            asm volatile("s_waitcnt vmcnt(0)" ::: "memory");
        }
        asm volatile("s_barrier" ::: "memory");
        const char* Ac = (const char*)As[t % 3];
        const char* Wc = (const char*)Ws[t % 3];
        s8v af[4], bw[2];
#pragma unroll
        for (int i = 0; i < 4; i++) {
            int r = wm * 64 + i * 16 + cl;
            af[i] = *(const s8v*)(Ac + r * 64 + ((quad ^ ((r >> 1) & 3)) * 16));
        }
#pragma unroll
        for (int j = 0; j < 2; j++) {
            int r = wn * 32 + j * 16 + cl;
            bw[j] = *(const s8v*)(Wc + r * 64 + ((quad ^ ((r >> 1) & 3)) * 16));
        }
#pragma unroll
        for (int i = 0; i < 4; i++)
#pragma unroll
            for (int j = 0; j < 2; j++)
                acc[i][j] = __builtin_amdgcn_mfma_f32_16x16x32_bf16(af[i], bw[j], acc[i][j], 0, 0, 0);
        asm volatile("s_barrier" ::: "memory");
    }

    const size_t ld = (size_t)ldo;
    constexpr bool STATS = (EPI == 0 || EPI == 5);
#pragma unroll
    for (int j = 0; j < 2; j++) {
        float ss = 0.f, ss2 = 0.f;
        const int n = bn * 64 + wn * 32 + j * 16 + cl;
        // ---- carry-weight tables (EPI 6 only) ----
        float Er[4], Ei[4], Cr[4], Cim[4];
        if constexpr (EPI == 6) {
            int h = n >> 1;
            float lr = lamp[h * 2], li = lamp[h * 2 + 1];
            float a2r = lr * lr - li * li, a2i = 2.f * lr * li;          // lam^2
            float a3r = a2r * lr - a2i * li, a3i = a2r * li + a2i * lr;  // lam^3
            float l4r = a2r * a2r - a2i * a2i, l4i = 2.f * a2r * a2i;    // lam^4
            float l8r = l4r * l4r - l4i * l4i, l8i = 2.f * l4r * l4i;
            float l12r = l8r * l4r - l8i * l4i, l12i = l8r * l4i + l8i * l4r;
            float Br = (quad == 0) ? l12r : (quad == 1) ? l8r : (quad == 2) ? l4r : 1.f;
            float Bi = (quad == 0) ? l12i : (quad == 1) ? l8i : (quad == 2) ? l4i : 0.f;
            float Ar[4] = { a3r, a2r, lr, 1.f };
            float Ai[4] = { a3i, a2i, li, 0.f };
#pragma unroll
            for (int r4 = 0; r4 < 4; r4++) {
                Er[r4] = Ar[r4] * Br - Ai[r4] * Bi;
                Ei[r4] = Ar[r4] * Bi + Ai[r4] * Br;
            }
            float l16r = l12r * l4r - l12i * l4i, l16i = l12r * l4i + l12i * l4r;
            float l32r = l16r * l16r - l16i * l16i, l32i = 2.f * l16r * l16i;
            float l48r = l32r * l16r - l32i * l16i, l48i = l32r * l16i + l32i * l16r;
            Cr[0] = l48r; Cim[0] = l48i;   // i=0 -> lam^48
            Cr[1] = l32r; Cim[1] = l32i;
            Cr[2] = l16r; Cim[2] = l16i;
            Cr[3] = 1.f;  Cim[3] = 0.f;
        }
        float Sr = 0.f, Si = 0.f;
#pragma unroll
        for (int i = 0; i < 4; i++) {
#pragma unroll
            for (int r4 = 0; r4 < 4; r4++) {
                int m = bm * 128 + wm * 64 + i * 16 + quad * 4 + r4;
                size_t idx = (size_t)m * ld + n;
                float v = acc[i][j][r4];
                if (EPI == 0) {
                    v += b2f(bias[n]);
                    outB[idx] = f2b(v);
                } else if (EPI == 2) {
                    v += b2f(Dv[n]) * (fstats[n] * b2f(aux[idx]) + fstats[256 + n]);
                    outB[idx] = f2b(v);
                } else if (EPI == 5) {
                    v += b2f(bias[n]) + b2f(aux[idx]);
                    outB[idx] = f2b(v);
                } else if (EPI == 6) {
                    v += fstats[n];
                    bf16 ob = f2b(v);
                    outB[idx] = ob;
                    float vr = b2f(ob);
                    float wr = Er[r4] * Cr[i] - Ei[r4] * Cim[i];
                    float wi = Er[r4] * Cim[i] + Ei[r4] * Cr[i];
                    Sr += vr * wr;
                    Si += vr * wi;
                }
                if (STATS) { ss += v; ss2 += v * v; }
            }
        }
        if constexpr (EPI == 6) {
            Sr += __shfl_xor(Sr, 16); Sr += __shfl_xor(Sr, 32);
            Si += __shfl_xor(Si, 16); Si += __shfl_xor(Si, 32);
            float pSr = __shfl_xor(Sr, 1), pSi = __shfl_xor(Si, 1);
            if (quad == 0 && (cl & 1) == 0) {
                size_t gc = (size_t)(bm * 2 + wm);      // global time-chunk
                size_t ci = (gc * 256 + (size_t)(n >> 1)) * 2;
                carry[ci]     = Sr - pSi;
                carry[ci + 1] = Si + pSr;
            }
        }
        if (STATS) {
            ss += __shfl_xor(ss, 16);  ss += __shfl_xor(ss, 32);
            ss2 += __shfl_xor(ss2, 16); ss2 += __shfl_xor(ss2, 32);
            if (lane < 16) {
                int nl = wn * 32 + j * 16 + lane;
                sred[wm * 64 + nl] = ss;
                sred[128 + wm * 64 + nl] = ss2;
            }
        }
    }
    if constexpr (STATS) {
        __syncthreads();
        if (tid < 64) {
            float sv = sred[tid] + sred[64 + tid];
            float sv2 = sred[128 + tid] + sred[192 + tid];
            spart[(size_t)bm * 256 + bn * 64 + tid] = sv;
            spart[131072 + (size_t)bm * 256 + bn * 64 + tid] = sv2;
        }
    }
}

// ---------------- fused GLU: TWO 128m x (64v+64g) tiles per block --------
// 4 waves each 64m x (32v+32g). 3-buffer ring 48KB; ring runs continuously
// across the tile boundary. Counted waits account for the 32 epilogue
// stores at the tile boundary (G in {8,9}: vmcnt(40)).
__global__ __launch_bounds__(256)
void glu_v8(const bf16* __restrict__ A, const bf16* __restrict__ W,
            bf16* __restrict__ outB, const bf16* __restrict__ bias)
{
    constexpr int KK = 256;
    constexpr int GT = 16;
    const int id = blockIdx.x;
    const int xcd = id & 7, q = id >> 3;
    const int nb = q & 7;
    const int mgrp = (q >> 3) * 8 + xcd;       // 0..255

    const int tid = threadIdx.x;
    const int lane = tid & 63, wv = tid >> 6;
    const int wm = wv >> 1, wn = wv & 1;
    const int quad = lane >> 4, cl = lane & 15;

    __shared__ __align__(16) short As[3][128 * 32];
    __shared__ __align__(16) short Vs[3][64 * 32];
    __shared__ __align__(16) short Gs[3][64 * 32];

    const char* Abase = (const char*)A;
    const char* Vb = (const char*)W + (size_t)(nb * 64) * ((size_t)KK * 2);
    const char* Gb = (const char*)W + (size_t)(512 + nb * 64) * ((size_t)KK * 2);
    constexpr int ldb = KK * 2;

    auto stage = [&](int G) {
        const int tile = G >> 3;
        const int kb = (G & 7) * 64;
        const int bi = G % 3;
        const char* Ab = Abase + (size_t)(mgrp * 2 + tile) * 128 * ((size_t)KK * 2);
#pragma unroll
        for (int it = 0; it < 2; ++it) {
            int Gt = it * 256 + tid;
            int r = Gt >> 2;
            int gl = (Gt & 3) ^ ((r >> 1) & 3);
            ld_g2l(Ab + (size_t)r * ldb + kb + gl * 16,
                   (char*)As[bi] + (it * 4 + wv) * 1024);
        }
        {
            int r = tid >> 2;
            int gl = (tid & 3) ^ ((r >> 1) & 3);
            ld_g2l(Vb + (size_t)r * ldb + kb + gl * 16, (char*)Vs[bi] + wv * 1024);
            ld_g2l(Gb + (size_t)r * ldb + kb + gl * 16, (char*)Gs[bi] + wv * 1024);
        }
    };

    f4v accv[4][2], accg[4][2];
#pragma unroll
    for (int i = 0; i < 4; i++)
#pragma unroll
        for (int j = 0; j < 2; j++) {
            accv[i][j] = (f4v){0.f, 0.f, 0.f, 0.f};
            accg[i][j] = (f4v){0.f, 0.f, 0.f, 0.f};
        }

    stage(0);
    stage(1);
#pragma unroll
    for (int G = 0; G < GT; ++G) {
        if (G + 2 < GT) {
            stage(G + 2);
            if (G == 8 || G == 9) {
                asm volatile("s_waitcnt vmcnt(40)" ::: "memory");
            } else {
                asm volatile("s_waitcnt vmcnt(8)" ::: "memory");
            }
        } else if (G + 1 < GT) {
            asm volatile("s_waitcnt vmcnt(4)" ::: "memory");
        } else {
            asm volatile("s_waitcnt vmcnt(0)" ::: "memory");
        }
        asm volatile("s_barrier" ::: "memory");
        const char* Ac = (const char*)As[G % 3];
        const char* Vc = (const char*)Vs[G % 3];
        const char* Gc = (const char*)Gs[G % 3];
        s8v af[4], bv[2], bg[2];
#pragma unroll
        for (int i = 0; i < 4; i++) {
            int r = wm * 64 + i * 16 + cl;
            af[i] = *(const s8v*)(Ac + r * 64 + ((quad ^ ((r >> 1) & 3)) * 16));
        }
#pragma unroll
        for (int j = 0; j < 2; j++) {
            int r = wn * 32 + j * 16 + cl;
            int off = r * 64 + ((quad ^ ((r >> 1) & 3)) * 16);
            bv[j] = *(const s8v*)(Vc + off);
            bg[j] = *(const s8v*)(Gc + off);
        }
#pragma unroll
        for (int i = 0; i < 4; i++)
#pragma unroll
            for (int j = 0; j < 2; j++) {
                accv[i][j] = __builtin_amdgcn_mfma_f32_16x16x32_bf16(af[i], bv[j], accv[i][j], 0, 0, 0);
                accg[i][j] = __builtin_amdgcn_mfma_f32_16x16x32_bf16(af[i], bg[j], accg[i][j], 0, 0, 0);
            }
        asm volatile("s_barrier" ::: "memory");

        if ((G & 7) == 7) {
            const int bm = mgrp * 2 + (G >> 3);
#pragma unroll
            for (int i = 0; i < 4; i++) {
#pragma unroll
                for (int j = 0; j < 2; j++) {
#pragma unroll
                    for (int r4 = 0; r4 < 4; r4++) {
                        int m = bm * 128 + wm * 64 + i * 16 + quad * 4 + r4;
                        int n = nb * 64 + wn * 32 + j * 16 + cl;
                        float v = accv[i][j][r4] + b2f(bias[n]);
                        float g = accg[i][j][r4] + b2f(bias[512 + n]);
                        outB[(size_t)m * 512 + n] = f2b(v * (1.f / (1.f + __expf(-g))));
                    }
                }
            }
            if (G + 1 < GT) {
#pragma unroll
                for (int i = 0; i < 4; i++)
#pragma unroll
                    for (int j = 0; j < 2; j++) {
                        accv[i][j] = (f4v){0.f, 0.f, 0.f, 0.f};
                        accg[i][j] = (f4v){0.f, 0.f, 0.f, 0.f};
                    }
            }
        }
    }
}

// ---------------- BatchNorm finish: partials -> affine tables -------------
__global__ void bn_finish2(const float* __restrict__ part, float* __restrict__ stats,
                           const bf16* __restrict__ sc, const bf16* __restrict__ bi) {
    int e = blockIdx.x;   // 256
    int t = threadIdx.x;
    float s = part[(size_t)t * 256 + e] + part[(size_t)(t + 256) * 256 + e];
    float s2 = part[131072 + (size_t)t * 256 + e] + part[131072 + (size_t)(t + 256) * 256 + e];
    __shared__ float rs[256], rs2[256];
    rs[t] = s; rs2[t] = s2;
    __syncthreads();
    for (int k = 128; k > 0; k >>= 1) {
        if (t < k) { rs[t] += rs[t + k]; rs2[t] += rs2[t + k]; }
        __syncthreads();
    }
    if (t == 0) {
        float mu = rs[0] * (1.f / 65536.f);
        float var = rs2[0] * (1.f / 65536.f) - mu * mu;
        float a = rsqrtf(var + 1e-5f) * b2f(sc[e]);
        stats[e] = a;
        stats[256 + e] = b2f(bi[e]) - mu * a;
    }
}

// wb[n,e] = B_?[h,e]*gamma[h]*a[e] with INTERLEAVED rows (n=2h -> re, 2h+1 -> im)
// + fused Bu bias: bubias[n] = gamma[h] * sum_e c[e]*B_?[h,e]
__global__ void pack_wb(const void* __restrict__ B_re, const void* __restrict__ B_im,
                        size_t off, const float* __restrict__ gam,
                        const float* __restrict__ stats,
                        bf16* __restrict__ out, float* __restrict__ bias_out,
                        const int* __restrict__ flag) {
    int f = *flag;
    int n = blockIdx.x;   // 512
    int e = threadIdx.x;
    int h = n >> 1;
    const void* src = (n & 1) ? B_im : B_re;
    float v = ldf(src, off + (size_t)h * 256 + e, f);
    out[(size_t)n * 256 + e] = f2b(v * gam[h] * stats[e]);
    __shared__ float rs[256];
    rs[e] = v * stats[256 + e];
    __syncthreads();
    for (int k = 128; k > 0; k >>= 1) {
        if (e < k) rs[e] += rs[e + k];
        __syncthreads();
    }
    if (e == 0) bias_out[n] = rs[0] * gam[h];
}

// all-layer weight packing up front: 6 layers x (wc 512 + w1t 1024 + w2t 512)
__global__ void pack_all(const void* __restrict__ C_re, const void* __restrict__ C_im,
                         const void* __restrict__ W1, const void* __restrict__ W2,
                         bf16* __restrict__ wc6, bf16* __restrict__ w1t6, bf16* __restrict__ w2t6,
                         const int* __restrict__ flag) {
    int f = *flag;
    int L = blockIdx.x >> 11;          // /2048
    int blk = blockIdx.x & 2047;
    size_t offC = (size_t)L * 65536, offW1 = (size_t)L * 262144, offW2 = (size_t)L * 131072;
    if (blk < 512) {
        // wc rows (k interleaved): k=2h -> C_re[e,h], k=2h+1 -> -C_im[e,h]
        int g = blk * 256 + threadIdx.x;
        int e = g >> 9, k = g & 511, h = k >> 1;
        float v = ldf((k & 1) ? C_im : C_re, offC + (size_t)e * 256 + h, f);
        wc6[(size_t)L * 131072 + g] = f2b((k & 1) ? -v : v);
    } else if (blk < 1536) {
        int g = (blk - 512) * 256 + threadIdx.x;
        int n = g >> 8, k = g & 255;
        w1t6[(size_t)L * 262144 + g] = f2b(ldf(W1, offW1 + (size_t)k * 1024 + n, f));
    } else {
        int g = (blk - 1536) * 256 + threadIdx.x;
        int n = g >> 9, k = g & 511;
        w2t6[(size_t)L * 131072 + g] = f2b(ldf(W2, offW2 + (size_t)k * 256 + n, f));
    }
}

// ---------------- LRU final: fused chunk-prefix + in-place scan ----------
__global__ void lru_final(bf16* __restrict__ bu, const float* __restrict__ carry,
                          const float* __restrict__ lam) {
    int gg = blockIdx.x * 256 + threadIdx.x;  // 131072
    int hp = gg & 127, c = (gg >> 7) & 31, b = gg >> 12;
    f4v lm = *(const f4v*)&lam[hp * 4];
    // lam^64 for both h of the pair (6 squarings)
    float q0r = lm[0], q0i = lm[1], q1r = lm[2], q1i = lm[3];
#pragma unroll
    for (int k = 0; k < 6; k++) {
        float n0 = q0r * q0r - q0i * q0i; q0i = 2.f * q0r * q0i; q0r = n0;
        float n1 = q1r * q1r - q1i * q1i; q1i = 2.f * q1r * q1i; q1r = n1;
    }
    float sr0 = 0.f, si0 = 0.f, sr1 = 0.f, si1 = 0.f;
    const f4v* cp = (const f4v*)(carry + ((size_t)b * 32) * 512) + hp;
    for (int cc = 0; cc < c; cc++) {
        f4v cv = *cp;
        float n0 = q0r * sr0 - q0i * si0 + cv[0];
        si0 = q0r * si0 + q0i * sr0 + cv[1]; sr0 = n0;
        float n1 = q1r * sr1 - q1i * si1 + cv[2];
        si1 = q1r * si1 + q1i * sr1 + cv[3]; sr1 = n1;
        cp += 128;   // next chunk (512 floats)
    }
    char* p = (char*)(bu + ((size_t)(b * TLEN + c * TCH)) * 512) + hp * 8;
    for (int t = 0; t < TCH; t++) {
        unsigned long long u = *(const unsigned long long*)p;
        float ur0 = bits2f((unsigned short)u), ui0 = bits2f((unsigned short)(u >> 16));
        float ur1 = bits2f((unsigned short)(u >> 32)), ui1 = bits2f((unsigned short)(u >> 48));
        float nr0 = lm[0] * sr0 - lm[1] * si0 + ur0;
        si0 = lm[0] * si0 + lm[1] * sr0 + ui0; sr0 = nr0;
        float nr1 = lm[2] * sr1 - lm[3] * si1 + ur1;
        si1 = lm[2] * si1 + lm[3] * sr1 + ui1; sr1 = nr1;
        unsigned long long w = (unsigned long long)f2bits(sr0)
                             | ((unsigned long long)f2bits(si0) << 16)
                             | ((unsigned long long)f2bits(sr1) << 32)
                             | ((unsigned long long)f2bits(si1) << 48);
        *(unsigned long long*)p = w;
        p += 1024;
    }
}

// ---------------- head (pool partials come from the last W2's BN-stats) ---
__global__ void head_k(const float* __restrict__ part, const bf16* __restrict__ W_out,
                       const bf16* __restrict__ b_out, void* __restrict__ out,
                       const int* __restrict__ flag) {
    int b = blockIdx.x;
    int tid = threadIdx.x;
    __shared__ float sp[256];
    __shared__ float red[160];
    float s = 0.f;
    for (int c = 0; c < 16; c++) s += part[((size_t)(b * 16 + c)) * 256 + tid];
    sp[tid] = s * (1.f / 2048.f);
    __syncthreads();
    if (tid < 160) {
        int o = tid >> 4, sg = tid & 15;
        float a = 0.f;
        for (int e = sg; e < 256; e += 16) a += sp[e] * b2f(W_out[e * 10 + o]);
        red[tid] = a;
    }
    __syncthreads();
    if (tid < 10) {
        float acc = b2f(b_out[tid]);
        for (int sg = 0; sg < 16; sg++) acc += red[tid * 16 + sg];
        if (*flag) ((float*)out)[b * 10 + tid] = acc;
        else       ((bf16*)out)[b * 10 + tid] = f2b(acc);
    }
}

extern "C" void kernel_launch(void* const* d_in, const int* in_sizes, int n_in,
                              void* d_out, int out_size, void* d_ws, size_t ws_size,
                              hipStream_t stream) {
    (void)in_sizes; (void)n_in; (void)out_size; (void)ws_size;
    const void* x      = d_in[0];
    const void* W_enc  = d_in[1];
    const void* b_enc  = d_in[2];
    const void* nu_log = d_in[3];
    const void* th_log = d_in[4];
    const void* B_re   = d_in[5];
    const void* B_im   = d_in[6];
    const void* C_re   = d_in[7];
    const void* C_im   = d_in[8];
    const void* Dp     = d_in[9];
    const void* W1     = d_in[10];
    const void* b1     = d_in[11];
    const void* W2     = d_in[12];
    const void* b2     = d_in[13];
    const void* bn_s   = d_in[14];
    const void* bn_b   = d_in[15];
    const void* W_out  = d_in[16];
    const void* b_out  = d_in[17];

    // workspace layout (~178 MB)
    char* w = (char*)d_ws;
    bf16* xc  = (bf16*)w; w += (size_t)MTOT * 256 * 2;   // residual stream
    bf16* y   = (bf16*)w; w += (size_t)MTOT * 256 * 2;   // residual anchor (= encoder out)
    bf16* hbn = (bf16*)w; w += (size_t)MTOT * 256 * 2;   // LRU out
    bf16* bu  = (bf16*)w; w += (size_t)MTOT * 512 * 2;   // Bu/hs (interleaved), GLU out
    float* stats  = (float*)w; w += 4096;                // a[256], c[256]
    float* bnpart = (float*)w; w += 1048576;             // stats partials (also pool partials)
    float* carry  = (float*)w; w += 2097152;             // 1024 chunks x 256 h x 2 fp32
    float* lamb   = (float*)w; w += 12288;               // 1536*2 fp32
    float* gamt   = (float*)w; w += 6144;                // 1536 fp32
    float* bubias = (float*)w; w += 2048;                // 512 fp32
    int*   flag   = (int*)w;  w += 256;
    bf16* wt_enc = (bf16*)w; w += 32768;
    bf16* wb   = (bf16*)w; w += 262144;
    bf16* wc6  = (bf16*)w; w += 6 * 262144;              // 1.57 MB
    bf16* w1t6 = (bf16*)w; w += 6 * 524288;              // 3.15 MB
    bf16* w2t6 = (bf16*)w; w += 6 * 262144;              // 1.57 MB
    bf16* b_encb = (bf16*)w; w += 512;
    bf16* Db     = (bf16*)w; w += 3072;
    bf16* b1b    = (bf16*)w; w += 12288;
    bf16* b2b    = (bf16*)w; w += 3072;
    bf16* bnsb   = (bf16*)w; w += 3072;
    bf16* bnbb   = (bf16*)w; w += 3072;
    bf16* Woutb  = (bf16*)w; w += 5120;
    bf16* boutb  = (bf16*)w; w += 32;
    bf16* xb = bu;  // f32->bf16 copy of x aliases bu (dead until first Bu GEMM)

    dim3 blk(256);
    detect_k<<<1, blk, 0, stream>>>((const unsigned short*)x, flag);
    cvt_k4<<<4096, blk, 0, stream>>>(x, xb, 4194304, flag);   // no-op when x is bf16
    setup_all<<<130, blk, 0, stream>>>(b_enc, Dp, b1, b2, bn_s, bn_b, W_out, b_out,
                                       nu_log, th_log, W_enc,
                                       b_encb, Db, b1b, b2b, bnsb, bnbb, Woutb, boutb,
                                       lamb, gamt, wt_enc, flag);
    pack_all<<<12288, blk, 0, stream>>>(C_re, C_im, W1, W2, wc6, w1t6, w2t6, flag);

    // encoder: [M,64] @ W_enc^T + b_enc -> y only (+ BN stats partials);
    // A chosen on device: flag ? xb : raw bf16 x
    gemm_v7<64, 4, 0><<<2048, blk, 0, stream>>>(xb, wt_enc, y, nullptr, 256,
                                                b_encb, nullptr, nullptr, nullptr, bnpart,
                                                nullptr, nullptr, (const bf16*)x, flag);
    for (int i = 0; i < 6; ++i) {
        const bf16* xin = (i == 0) ? y : xc;   // residual-stream source for this layer
        bn_finish2<<<256, blk, 0, stream>>>(bnpart, stats, bnsb + i * 256, bnbb + i * 256);
        pack_wb<<<512, blk, 0, stream>>>(B_re, B_im, (size_t)i * 65536, gamt + i * 256,
                                         stats, wb, bubias, flag);
        // Bu = BN(xin) @ (gamma*[B;B])^T -> bu [M,512] + fused chunk-carry
        gemm_v7<256, 8, 6><<<4096, blk, 0, stream>>>(xin, wb, bu, nullptr, 512,
                                                     nullptr, nullptr, nullptr, bubias, nullptr,
                                                     lamb + i * 512, carry, nullptr, nullptr);
        // scan (prefix fused): bu <- hs in place
        lru_final<<<512, blk, 0, stream>>>(bu, carry, lamb + i * 512);
        // lru_out = hs @ [C_re;-C_im]^T + D*(a*xin+c) -> hbn [M,256]
        gemm_v7<512, 4, 2><<<2048, blk, 0, stream>>>(bu, wc6 + (size_t)i * 131072, hbn, nullptr, 256,
                                                     nullptr, Db + i * 256, xin, stats, nullptr,
                                                     nullptr, nullptr, nullptr, nullptr);
        // fused GLU MLP: bu = (hbn@W1v+b1v)*sigmoid(hbn@W1g+b1g)  [M,512]
        glu_v8<<<2048, blk, 0, stream>>>(hbn, w1t6 + (size_t)i * 262144, bu, b1b + i * 1024);
        // xc = glu @ W2^T + b2 + y (+ BN stats / pool partials for next stage)
        gemm_v7<512, 4, 5><<<2048, blk, 0, stream>>>(bu, w2t6 + (size_t)i * 131072, xc, nullptr, 256,
                                                     b2b + i * 256, nullptr, y, nullptr, bnpart,
                                                     nullptr, nullptr, nullptr, nullptr);
    }
    head_k<<<32, blk, 0, stream>>>(bnpart, Woutb, boutb, d_out, flag);
}